// Round 1
// baseline (3694.848 us; speedup 1.0000x reference)
//
#include <hip/hip_runtime.h>
#include <math.h>

#define S_LEN 8192
#define B_N   16
#define C_N   64
#define NBC   (B_N * C_N)   // 1024 rows
#define L1 4103
#define L2 2059
#define L3 1037
#define L4 526

// sym16 decomposition filters (from reference DEC_LO; DEC_HI[n] = (-1)^(15-n)*DEC_LO[15-n])
__constant__ float c_dlo[16] = {
    -0.0033824159510061256f, -0.0005421323317911481f,  0.03169508781149298f,
     0.007607487324917605f,  -0.1432942383508097f,    -0.061273359067658524f,
     0.4813596512583722f,     0.7771857517005235f,     0.3644418948353314f,
    -0.05194583810770904f,   -0.027219029917056003f,   0.049137179673607506f,
     0.003808752013890615f,  -0.01495225833704823f,   -0.0003029205147213668f,
     0.0018899503327594609f
};
__constant__ float c_dhi[16] = {
    -0.0018899503327594609f, -0.0003029205147213668f,  0.01495225833704823f,
     0.003808752013890615f,  -0.049137179673607506f,  -0.027219029917056003f,
     0.05194583810770904f,    0.3644418948353314f,    -0.7771857517005235f,
     0.4813596512583722f,     0.061273359067658524f,  -0.1432942383508097f,
    -0.007607487324917605f,   0.03169508781149298f,    0.0005421323317911481f,
    -0.0033824159510061256f
};

__device__ __forceinline__ float gelu_exact(float x) {
    return 0.5f * x * (1.0f + erff(x * 0.70710678118654752f));
}

// ---------------- lift: h[b,o,s] = w[o,0]*x[b,s] + w[o,1]*grid[s] + bias[o] ----------------
__global__ __launch_bounds__(256) void lift_kernel(const float* __restrict__ x,
                                                   const float* __restrict__ w,
                                                   const float* __restrict__ bias,
                                                   float* __restrict__ out) {
    int idx = blockIdx.x * 256 + threadIdx.x;           // < B*C*S = 8388608
    int s = idx & (S_LEN - 1);
    int r = idx >> 13;                                  // b*C + o
    int o = r & (C_N - 1);
    int b = r >> 6;
    float g = -1.0f + 2.0f * (float)s / (float)(S_LEN - 1);
    out[idx] = fmaf(w[o * 2 + 0], x[b * S_LEN + s], fmaf(w[o * 2 + 1], g, bias[o]));
}

// ---------------- instance norm over last axis, one block per (b,c) row ----------------
__global__ __launch_bounds__(256) void inorm_kernel(const float* __restrict__ in,
                                                    float* __restrict__ out) {
    const int base = blockIdx.x * S_LEN;
    const int tid = threadIdx.x;
    float v[32];
    float s = 0.f, ss = 0.f;
#pragma unroll
    for (int i = 0; i < 32; ++i) {
        float xv = in[base + tid + i * 256];
        v[i] = xv;
        s += xv;
        ss = fmaf(xv, xv, ss);
    }
    for (int off = 32; off > 0; off >>= 1) {
        s  += __shfl_down(s, off, 64);
        ss += __shfl_down(ss, off, 64);
    }
    __shared__ float sh[8];
    int lane = tid & 63, wv = tid >> 6;
    if (lane == 0) { sh[wv] = s; sh[4 + wv] = ss; }
    __syncthreads();
    float tot  = sh[0] + sh[1] + sh[2] + sh[3];
    float tot2 = sh[4] + sh[5] + sh[6] + sh[7];
    float mean = tot * (1.0f / S_LEN);
    float var  = tot2 * (1.0f / S_LEN) - mean * mean;
    float inv  = rsqrtf(var + 1e-5f);
#pragma unroll
    for (int i = 0; i < 32; ++i)
        out[base + tid + i * 256] = (v[i] - mean) * inv;
}

// ---------------- conv1d k=3 pad=1, Cin=Cout=64, LDS tile of 64 pos + halo ----------------
__global__ __launch_bounds__(256) void conv3_kernel(const float* __restrict__ in,
                                                    float* __restrict__ out,
                                                    const float* __restrict__ W,   // (64,64,3)
                                                    const float* __restrict__ bias) {
    __shared__ float sx[64][66];
    const int b = blockIdx.y;
    const int l0 = blockIdx.x * 64;
    const int tid = threadIdx.x;
    for (int e = tid; e < 64 * 66; e += 256) {
        int c = e / 66, p = e % 66;
        int l = l0 + p - 1;
        sx[c][p] = (l >= 0 && l < S_LEN) ? in[(b * 64 + c) * S_LEN + l] : 0.f;
    }
    __syncthreads();
    const int t = tid & 63;
    const int obase = (tid >> 6) * 16;
    float acc[16];
#pragma unroll
    for (int j = 0; j < 16; ++j) acc[j] = bias[obase + j];
    for (int c4 = 0; c4 < 16; ++c4) {
        float a0[4], a1[4], a2[4];
#pragma unroll
        for (int q = 0; q < 4; ++q) {
            a0[q] = sx[4 * c4 + q][t];
            a1[q] = sx[4 * c4 + q][t + 1];
            a2[q] = sx[4 * c4 + q][t + 2];
        }
#pragma unroll
        for (int j = 0; j < 16; ++j) {
            const float* wp = W + (obase + j) * 192 + c4 * 12;
            float4 q0 = *(const float4*)(wp);
            float4 q1 = *(const float4*)(wp + 4);
            float4 q2 = *(const float4*)(wp + 8);
            acc[j] += a0[0] * q0.x + a1[0] * q0.y + a2[0] * q0.z
                    + a0[1] * q0.w + a1[1] * q1.x + a2[1] * q1.y
                    + a0[2] * q1.z + a1[2] * q1.w + a2[2] * q2.x
                    + a0[3] * q2.y + a1[3] * q2.z + a2[3] * q2.w;
        }
    }
#pragma unroll
    for (int j = 0; j < 16; ++j)
        out[(b * 64 + obase + j) * S_LEN + l0 + t] = acc[j];
}

// ---------------- channel mix: out[b,o,l] = act( sum_c in[b,c,l]*W[o,c] + bias[o] ) (+out) --
template <int CIN, int COUT, int ACT, int RES>
__global__ __launch_bounds__(256) void mix_kernel(const float* __restrict__ in,
                                                  float* __restrict__ out,
                                                  const float* __restrict__ W,
                                                  const float* __restrict__ bias,
                                                  int L) {
    constexpr int OPT = (COUT * 64) / 256;
    __shared__ float sx[CIN][64];
    const int b = blockIdx.y;
    const int l0 = blockIdx.x * 64;
    const int tid = threadIdx.x;
    for (int e = tid; e < CIN * 64; e += 256) {
        int c = e >> 6, t = e & 63;
        int l = l0 + t;
        sx[c][t] = (l < L) ? in[(b * CIN + c) * L + l] : 0.f;
    }
    __syncthreads();
    const int t = tid & 63;
    const int obase = (tid >> 6) * OPT;
    if (l0 + t >= L) return;
    float acc[OPT];
#pragma unroll
    for (int j = 0; j < OPT; ++j) acc[j] = bias[obase + j];
    for (int c4 = 0; c4 < CIN / 4; ++c4) {
        float x0 = sx[4 * c4 + 0][t];
        float x1 = sx[4 * c4 + 1][t];
        float x2 = sx[4 * c4 + 2][t];
        float x3 = sx[4 * c4 + 3][t];
#pragma unroll
        for (int j = 0; j < OPT; ++j) {
            float4 w = *(const float4*)(W + (obase + j) * CIN + 4 * c4);
            acc[j] = fmaf(x0, w.x, fmaf(x1, w.y, fmaf(x2, w.z, fmaf(x3, w.w, acc[j]))));
        }
    }
#pragma unroll
    for (int j = 0; j < OPT; ++j) {
        float v = acc[j];
        if (ACT == 1) v = gelu_exact(v);
        float* p = out + (b * COUT + obase + j) * L + l0 + t;
        if (RES) v += *p;
        *p = v;
    }
}

// ---------------- DWT one level: symmetric pad, stride 2, 16 taps ----------------
__global__ __launch_bounds__(256) void dwt_kernel(const float* __restrict__ in,
                                                  float* __restrict__ a_out,
                                                  float* __restrict__ d_out,
                                                  int Sin, int Lout) {
    int row = blockIdx.y;
    int t = blockIdx.x * 256 + threadIdx.x;
    if (t >= Lout) return;
    const float* x = in + row * Sin;
    float lo = 0.f, hi = 0.f;
#pragma unroll
    for (int k = 0; k < 16; ++k) {
        int i = 2 * t + k - 14;
        i = (i < 0) ? (-1 - i) : i;
        i = (i >= Sin) ? (2 * Sin - 1 - i) : i;
        float v = x[i];
        lo = fmaf(v, c_dlo[15 - k], lo);
        hi = fmaf(v, c_dhi[15 - k], hi);
    }
    a_out[row * Lout + t] = lo;
    d_out[row * Lout + t] = hi;
}

// ---------------- IDWT one level: lhs_dilation 2, pad 1, 16 taps ----------------
__global__ __launch_bounds__(256) void idwt_kernel(const float* __restrict__ a,
                                                   const float* __restrict__ d,
                                                   float* __restrict__ out,
                                                   int Lc, int sA, int Lout) {
    int row = blockIdx.y;
    int t = blockIdx.x * 256 + threadIdx.x;
    if (t >= Lout) return;
    const float* ar = a + row * sA;
    const float* dr = d + row * Lc;
    int m0 = t >> 1;
    float acc = 0.f;
    if ((t & 1) == 0) {
#pragma unroll
        for (int j = 0; j < 8; ++j) {
            int m = m0 + j;
            if (m < Lc) acc += ar[m] * c_dlo[2 * j + 1] + dr[m] * c_dlo[14 - 2 * j];
        }
    } else {
#pragma unroll
        for (int j = 0; j < 8; ++j) {
            int m = m0 + j;
            if (m < Lc) acc += ar[m] * c_dlo[2 * j] - dr[m] * c_dlo[15 - 2 * j];
        }
    }
    out[row * Lout + t] = acc;
}

// ---------------- xo = h + gelu(xw + xs), in place on h ----------------
__global__ __launch_bounds__(256) void fuse_gelu_kernel(float* __restrict__ h,
                                                        const float* __restrict__ xw,
                                                        const float* __restrict__ xs) {
    int i = blockIdx.x * 256 + threadIdx.x;
    float u = xw[i] + xs[i];
    h[i] = h[i] + gelu_exact(u);
}

extern "C" void kernel_launch(void* const* d_in, const int* in_sizes, int n_in,
                              void* d_out, int out_size, void* d_ws, size_t ws_size,
                              hipStream_t stream) {
    const float* x       = (const float*)d_in[0];
    const float* lift_w  = (const float*)d_in[1];
    const float* lift_b  = (const float*)d_in[2];
    const float* blk_w_w = (const float*)d_in[3];   // (4,64,64,3)
    const float* blk_w_b = (const float*)d_in[4];   // (4,64)
    const float* blk_ca_w= (const float*)d_in[5];   // (4,64,64)
    const float* blk_ca_b= (const float*)d_in[6];   // (4,64)
    const float* blk_cd_w= (const float*)d_in[7];   // (4,4,64,64)
    const float* blk_cd_b= (const float*)d_in[8];   // (4,4,64)
    const float* blk_m1_w= (const float*)d_in[9];   // (4,128,64)
    const float* blk_m1_b= (const float*)d_in[10];  // (4,128)
    const float* blk_m2_w= (const float*)d_in[11];  // (4,64,128)
    const float* blk_m2_b= (const float*)d_in[12];  // (4,64)
    const float* p1_w    = (const float*)d_in[13];  // (32,64)
    const float* p1_b    = (const float*)d_in[14];
    const float* p2_w    = (const float*)d_in[15];  // (64,32)
    const float* p2_b    = (const float*)d_in[16];

    float* ws = (float*)d_ws;
    const size_t T32 = (size_t)NBC * S_LEN;         // 8388608
    float* A  = ws;                                  // h / xo (persistent)
    float* Bb = ws + T32;                            // xn / xon / p1-out
    float* Cc = ws + 2 * T32;                        // xs
    float* Dd = ws + 3 * T32;                        // xw
    float* M  = Cc;                                  // MLP mid (B,128,S) aliases C+D
    float* d1 = ws + 4 * T32;                        // wavelet detail store
    float* d2 = d1 + (size_t)NBC * L1;
    float* d3 = d2 + (size_t)NBC * L2;
    float* d4 = d3 + (size_t)NBC * L3;
    float* ap0 = d4 + (size_t)NBC * L4;              // a ping-pong (stride up to 4104)
    float* ap1 = ap0 + (size_t)NBC * 4104;

    dim3 blk(256);

    lift_kernel<<<(B_N * C_N * S_LEN) / 256, blk, 0, stream>>>(x, lift_w, lift_b, A);

    for (int i = 0; i < 4; ++i) {
        const float* w_w  = blk_w_w  + (size_t)i * 64 * 64 * 3;
        const float* w_b  = blk_w_b  + (size_t)i * 64;
        const float* ca_w = blk_ca_w + (size_t)i * 64 * 64;
        const float* ca_b = blk_ca_b + (size_t)i * 64;
        const float* cd_w = blk_cd_w + (size_t)i * 4 * 64 * 64;
        const float* cd_b = blk_cd_b + (size_t)i * 4 * 64;
        const float* m1_w = blk_m1_w + (size_t)i * 128 * 64;
        const float* m1_b = blk_m1_b + (size_t)i * 128;
        const float* m2_w = blk_m2_w + (size_t)i * 64 * 128;
        const float* m2_b = blk_m2_b + (size_t)i * 64;

        inorm_kernel<<<NBC, blk, 0, stream>>>(A, Bb);
        conv3_kernel<<<dim3(S_LEN / 64, B_N), blk, 0, stream>>>(Bb, Cc, w_w, w_b);

        dwt_kernel<<<dim3((L1 + 255) / 256, NBC), blk, 0, stream>>>(Bb,  ap0, d1, S_LEN, L1);
        dwt_kernel<<<dim3((L2 + 255) / 256, NBC), blk, 0, stream>>>(ap0, ap1, d2, L1, L2);
        dwt_kernel<<<dim3((L3 + 255) / 256, NBC), blk, 0, stream>>>(ap1, ap0, d3, L2, L3);
        dwt_kernel<<<dim3((L4 + 255) / 256, NBC), blk, 0, stream>>>(ap0, ap1, d4, L3, L4);

        // channel mixes (in-place): ca on a4; cd[0]->d4, cd[1]->d3, cd[2]->d2, cd[3]->d1
        mix_kernel<64, 64, 0, 0><<<dim3((L4 + 63) / 64, B_N), blk, 0, stream>>>(ap1, ap1, ca_w, ca_b, L4);
        mix_kernel<64, 64, 0, 0><<<dim3((L4 + 63) / 64, B_N), blk, 0, stream>>>(d4, d4, cd_w + 0 * 4096, cd_b + 0 * 64, L4);
        mix_kernel<64, 64, 0, 0><<<dim3((L3 + 63) / 64, B_N), blk, 0, stream>>>(d3, d3, cd_w + 1 * 4096, cd_b + 1 * 64, L3);
        mix_kernel<64, 64, 0, 0><<<dim3((L2 + 63) / 64, B_N), blk, 0, stream>>>(d2, d2, cd_w + 2 * 4096, cd_b + 2 * 64, L2);
        mix_kernel<64, 64, 0, 0><<<dim3((L1 + 63) / 64, B_N), blk, 0, stream>>>(d1, d1, cd_w + 3 * 4096, cd_b + 3 * 64, L1);

        // waverec: lengths 526->1038->2060->4104->8192 (a truncated to d's length each step)
        idwt_kernel<<<dim3((1038 + 255) / 256, NBC), blk, 0, stream>>>(ap1, d4, ap0, L4, L4,  1038);
        idwt_kernel<<<dim3((2060 + 255) / 256, NBC), blk, 0, stream>>>(ap0, d3, ap1, L3, 1038, 2060);
        idwt_kernel<<<dim3((4104 + 255) / 256, NBC), blk, 0, stream>>>(ap1, d2, ap0, L2, 2060, 4104);
        idwt_kernel<<<dim3((S_LEN + 255) / 256, NBC), blk, 0, stream>>>(ap0, d1, Dd, L1, 4104, S_LEN);

        fuse_gelu_kernel<<<(B_N * C_N * S_LEN) / 256, blk, 0, stream>>>(A, Dd, Cc);

        inorm_kernel<<<NBC, blk, 0, stream>>>(A, Bb);
        mix_kernel<64, 128, 1, 0><<<dim3(S_LEN / 64, B_N), blk, 0, stream>>>(Bb, M, m1_w, m1_b, S_LEN);
        mix_kernel<128, 64, 0, 1><<<dim3(S_LEN / 64, B_N), blk, 0, stream>>>(M, A, m2_w, m2_b, S_LEN);
    }

    mix_kernel<64, 32, 1, 0><<<dim3(S_LEN / 64, B_N), blk, 0, stream>>>(A, Bb, p1_w, p1_b, S_LEN);
    mix_kernel<32, 64, 0, 0><<<dim3(S_LEN / 64, B_N), blk, 0, stream>>>(Bb, (float*)d_out, p2_w, p2_b, S_LEN);
}

// Round 2
// 2142.474 us; speedup vs baseline: 1.7246x; 1.7246x over previous
//
#include <hip/hip_runtime.h>
#include <math.h>

#define S_LEN 8192
#define B_N   16
#define NBC   1024          // B*C rows
#define L1v 4103
#define L2v 2059
#define L3v 1037
#define L4v 526
#define LP1 4104
#define LP2 2060
#define LP3 1040
#define LP4 528

__constant__ float c_dlo[16] = {
    -0.0033824159510061256f, -0.0005421323317911481f,  0.03169508781149298f,
     0.007607487324917605f,  -0.1432942383508097f,    -0.061273359067658524f,
     0.4813596512583722f,     0.7771857517005235f,     0.3644418948353314f,
    -0.05194583810770904f,   -0.027219029917056003f,   0.049137179673607506f,
     0.003808752013890615f,  -0.01495225833704823f,   -0.0003029205147213668f,
     0.0018899503327594609f
};
__constant__ float c_dhi[16] = {
    -0.0018899503327594609f, -0.0003029205147213668f,  0.01495225833704823f,
     0.003808752013890615f,  -0.049137179673607506f,  -0.027219029917056003f,
     0.05194583810770904f,    0.3644418948353314f,    -0.7771857517005235f,
     0.4813596512583722f,     0.061273359067658524f,  -0.1432942383508097f,
    -0.007607487324917605f,   0.03169508781149298f,    0.0005421323317911481f,
    -0.0033824159510061256f
};

__device__ __forceinline__ float gelu1(float x) {
    return 0.5f * x * (1.0f + erff(x * 0.70710678118654752f));
}
__device__ __forceinline__ float4 gelu4(float4 v) {
    v.x = gelu1(v.x); v.y = gelu1(v.y); v.z = gelu1(v.z); v.w = gelu1(v.w);
    return v;
}
__device__ __forceinline__ void fma4(float4& a, float w, const float4& x) {
    a.x = fmaf(w, x.x, a.x); a.y = fmaf(w, x.y, a.y);
    a.z = fmaf(w, x.z, a.z); a.w = fmaf(w, x.w, a.w);
}
__device__ __forceinline__ float4 load4g(const float* __restrict__ row, int l, int L) {
    float4 v;
    if (l >= 0 && l + 3 < L) {
        v = *(const float4*)(row + l);
    } else {
        v.x = (l     >= 0 && l     < L) ? row[l]     : 0.f;
        v.y = (l + 1 >= 0 && l + 1 < L) ? row[l + 1] : 0.f;
        v.z = (l + 2 >= 0 && l + 2 < L) ? row[l + 2] : 0.f;
        v.w = (l + 3 >= 0 && l + 3 < L) ? row[l + 3] : 0.f;
    }
    return v;
}
__device__ __forceinline__ void store4g(float* __restrict__ row, int l, int L, float4 v) {
    if (l + 3 < L) {
        *(float4*)(row + l) = v;
    } else {
        if (l     < L) row[l]     = v.x;
        if (l + 1 < L) row[l + 1] = v.y;
        if (l + 2 < L) row[l + 2] = v.z;
        if (l + 3 < L) row[l + 3] = v.w;
    }
}

// ---------------- lift ----------------
__global__ __launch_bounds__(256) void lift_kernel(const float* __restrict__ x,
                                                   const float* __restrict__ w,
                                                   const float* __restrict__ bias,
                                                   float* __restrict__ out) {
    int idx = blockIdx.x * 256 + threadIdx.x;
    int s = idx & (S_LEN - 1);
    int r = idx >> 13;
    int o = r & 63;
    int b = r >> 6;
    float g = -1.0f + 2.0f * (float)s / (float)(S_LEN - 1);
    out[idx] = fmaf(w[o * 2 + 0], x[b * S_LEN + s], fmaf(w[o * 2 + 1], g, bias[o]));
}

// ---------------- instance norm ----------------
__global__ __launch_bounds__(256) void inorm_kernel(const float* __restrict__ in,
                                                    float* __restrict__ out) {
    const int base = blockIdx.x * S_LEN;
    const int tid = threadIdx.x;
    float v[32];
    float s = 0.f, ss = 0.f;
#pragma unroll
    for (int i = 0; i < 32; ++i) {
        float xv = in[base + tid + i * 256];
        v[i] = xv;
        s += xv;
        ss = fmaf(xv, xv, ss);
    }
    for (int off = 32; off > 0; off >>= 1) {
        s  += __shfl_down(s, off, 64);
        ss += __shfl_down(ss, off, 64);
    }
    __shared__ float sh[8];
    int lane = tid & 63, wv = tid >> 6;
    if (lane == 0) { sh[wv] = s; sh[4 + wv] = ss; }
    __syncthreads();
    float tot  = sh[0] + sh[1] + sh[2] + sh[3];
    float tot2 = sh[4] + sh[5] + sh[6] + sh[7];
    float mean = tot * (1.0f / S_LEN);
    float var  = tot2 * (1.0f / S_LEN) - mean * mean;
    float inv  = rsqrtf(var + 1e-5f);
#pragma unroll
    for (int i = 0; i < 32; ++i)
        out[base + tid + i * 256] = (v[i] - mean) * inv;
}

// ---------------- conv1d k=3, C=64, LDS-staged weights, reg-blocked 8o x 8l ----------------
__device__ __forceinline__ void conv_fma(float4& acc, float w0, float w1, float w2,
                                         float xm, const float4& xv, float xp) {
    acc.x = fmaf(w0, xm,   fmaf(w1, xv.x, fmaf(w2, xv.y, acc.x)));
    acc.y = fmaf(w0, xv.x, fmaf(w1, xv.y, fmaf(w2, xv.z, acc.y)));
    acc.z = fmaf(w0, xv.y, fmaf(w1, xv.z, fmaf(w2, xv.w, acc.z)));
    acc.w = fmaf(w0, xv.z, fmaf(w1, xv.w, fmaf(w2, xp,   acc.w)));
}

__global__ __launch_bounds__(256) void conv3_kernel(const float* __restrict__ in,
                                                    float* __restrict__ out,
                                                    const float* __restrict__ W,   // (64,64,3)
                                                    const float* __restrict__ bias) {
    __shared__ float sx[32 * 264];   // 32 channels x [l0-4, l0+260)
    __shared__ float sw[32 * 192];   // [cc][k][o]
    const int b = blockIdx.y;
    const int l0 = blockIdx.x * 256;
    const int tid = threadIdx.x;
    const int og = tid >> 5;         // 0..7
    const int lg = tid & 31;         // 0..31

    float4 acc_a[8], acc_b[8];
#pragma unroll
    for (int j = 0; j < 8; ++j) {
        float bv = bias[og * 8 + j];
        acc_a[j] = make_float4(bv, bv, bv, bv);
        acc_b[j] = acc_a[j];
    }

    for (int ch = 0; ch < 2; ++ch) {
        const int c0 = ch * 32;
        if (ch) __syncthreads();
        for (int e = tid; e < 32 * 66; e += 256) {
            int cc = e / 66, p = e % 66;
            int l = l0 - 4 + p * 4;
            const float* row = in + ((size_t)(b * 64 + c0 + cc)) * S_LEN;
            *(float4*)(sx + cc * 264 + p * 4) = load4g(row, l, S_LEN);
        }
        for (int e = tid; e < 32 * 192; e += 256) {
            int cc = e / 192, r = e % 192;
            int k = r >> 6, o = r & 63;
            sw[cc * 192 + k * 64 + o] = W[o * 192 + (c0 + cc) * 3 + k];
        }
        __syncthreads();
#pragma unroll 2
        for (int cc = 0; cc < 32; ++cc) {
            const float* sxr = sx + cc * 264;
            const int ia = 4 + lg * 4;
            float  xm_a = sxr[ia - 1];
            float4 xva  = *(const float4*)(sxr + ia);
            float  xp_a = sxr[ia + 4];
            float  xm_b = sxr[ia + 127];
            float4 xvb  = *(const float4*)(sxr + ia + 128);
            float  xp_b = sxr[ia + 132];
            const float* swp = sw + cc * 192 + og * 8;
            float4 k0a = *(const float4*)(swp);
            float4 k0b = *(const float4*)(swp + 4);
            float4 k1a = *(const float4*)(swp + 64);
            float4 k1b = *(const float4*)(swp + 68);
            float4 k2a = *(const float4*)(swp + 128);
            float4 k2b = *(const float4*)(swp + 132);
            conv_fma(acc_a[0], k0a.x, k1a.x, k2a.x, xm_a, xva, xp_a);
            conv_fma(acc_b[0], k0a.x, k1a.x, k2a.x, xm_b, xvb, xp_b);
            conv_fma(acc_a[1], k0a.y, k1a.y, k2a.y, xm_a, xva, xp_a);
            conv_fma(acc_b[1], k0a.y, k1a.y, k2a.y, xm_b, xvb, xp_b);
            conv_fma(acc_a[2], k0a.z, k1a.z, k2a.z, xm_a, xva, xp_a);
            conv_fma(acc_b[2], k0a.z, k1a.z, k2a.z, xm_b, xvb, xp_b);
            conv_fma(acc_a[3], k0a.w, k1a.w, k2a.w, xm_a, xva, xp_a);
            conv_fma(acc_b[3], k0a.w, k1a.w, k2a.w, xm_b, xvb, xp_b);
            conv_fma(acc_a[4], k0b.x, k1b.x, k2b.x, xm_a, xva, xp_a);
            conv_fma(acc_b[4], k0b.x, k1b.x, k2b.x, xm_b, xvb, xp_b);
            conv_fma(acc_a[5], k0b.y, k1b.y, k2b.y, xm_a, xva, xp_a);
            conv_fma(acc_b[5], k0b.y, k1b.y, k2b.y, xm_b, xvb, xp_b);
            conv_fma(acc_a[6], k0b.z, k1b.z, k2b.z, xm_a, xva, xp_a);
            conv_fma(acc_b[6], k0b.z, k1b.z, k2b.z, xm_b, xvb, xp_b);
            conv_fma(acc_a[7], k0b.w, k1b.w, k2b.w, xm_a, xva, xp_a);
            conv_fma(acc_b[7], k0b.w, k1b.w, k2b.w, xm_b, xvb, xp_b);
        }
    }
#pragma unroll
    for (int j = 0; j < 8; ++j) {
        float* row = out + ((size_t)(b * 64 + og * 8 + j)) * S_LEN + l0;
        *(float4*)(row + lg * 4)       = acc_a[j];
        *(float4*)(row + 128 + lg * 4) = acc_b[j];
    }
}

// ---------------- channel mix GEMM: out[b,o,l] = act(sum_c W[o,c] in[b,c,l] + bias) (+res) --
template <int CIN, int COUT, int TO, int ACT, int RES>
__global__ __launch_bounds__(256) void mix_kernel(const float* __restrict__ in,
                                                  float* __restrict__ out,
                                                  const float* __restrict__ W,
                                                  const float* __restrict__ bias,
                                                  int L, int LP) {
    constexpr int NOG = COUT / TO;
    constexpr int NLG = 256 / NOG;
    constexpr int LT  = NLG * 8;
    constexpr int KC  = (CIN < 32) ? CIN : 32;
    constexpr int NCH = CIN / KC;
    __shared__ float sx[KC * LT];
    __shared__ float sw[KC * COUT];
    const int b = blockIdx.y;
    const int l0 = blockIdx.x * LT;
    const int tid = threadIdx.x;
    const int og = tid / NLG;
    const int lg = tid % NLG;
    const int la = l0 + lg * 4;
    const int lb = la + NLG * 4;

    float4 acc_a[TO], acc_b[TO];
#pragma unroll
    for (int j = 0; j < TO; ++j) {
        float bv = bias[og * TO + j];
        acc_a[j] = make_float4(bv, bv, bv, bv);
        acc_b[j] = acc_a[j];
    }

    for (int ch = 0; ch < NCH; ++ch) {
        const int c0 = ch * KC;
        if (ch) __syncthreads();
        for (int e = tid; e < KC * LT / 4; e += 256) {
            const int cc = e / (LT / 4);
            const int p  = e % (LT / 4);
            const int l  = l0 + p * 4;
            const float* row = in + ((size_t)(b * CIN + c0 + cc)) * LP;
            *(float4*)(sx + cc * LT + p * 4) = load4g(row, l, L);
        }
        for (int e = tid; e < KC * COUT; e += 256) {
            const int cc = e / COUT;
            const int o  = e % COUT;
            sw[cc * COUT + o] = W[o * CIN + c0 + cc];
        }
        __syncthreads();
#pragma unroll 4
        for (int cc = 0; cc < KC; ++cc) {
            const float4 xa = *(const float4*)(sx + cc * LT + lg * 4);
            const float4 xb = *(const float4*)(sx + cc * LT + NLG * 4 + lg * 4);
            const float* swp = sw + cc * COUT + og * TO;
            const float4 w0 = *(const float4*)(swp);
            fma4(acc_a[0], w0.x, xa); fma4(acc_b[0], w0.x, xb);
            fma4(acc_a[1], w0.y, xa); fma4(acc_b[1], w0.y, xb);
            fma4(acc_a[2], w0.z, xa); fma4(acc_b[2], w0.z, xb);
            fma4(acc_a[3], w0.w, xa); fma4(acc_b[3], w0.w, xb);
            if constexpr (TO == 8) {
                const float4 w1 = *(const float4*)(swp + 4);
                fma4(acc_a[4], w1.x, xa); fma4(acc_b[4], w1.x, xb);
                fma4(acc_a[5], w1.y, xa); fma4(acc_b[5], w1.y, xb);
                fma4(acc_a[6], w1.z, xa); fma4(acc_b[6], w1.z, xb);
                fma4(acc_a[7], w1.w, xa); fma4(acc_b[7], w1.w, xb);
            }
        }
    }
#pragma unroll
    for (int j = 0; j < TO; ++j) {
        float* row = out + ((size_t)(b * COUT + og * TO + j)) * LP;
        float4 va = acc_a[j], vb = acc_b[j];
        if (ACT) { va = gelu4(va); vb = gelu4(vb); }
        if (RES) {
            float4 ra = load4g(row, la, L), rb = load4g(row, lb, L);
            va.x += ra.x; va.y += ra.y; va.z += ra.z; va.w += ra.w;
            vb.x += rb.x; vb.y += rb.y; vb.z += rb.z; vb.w += rb.w;
        }
        store4g(row, la, L, va);
        store4g(row, lb, L, vb);
    }
}

// ---------------- DWT one level ----------------
__global__ __launch_bounds__(256) void dwt_kernel(const float* __restrict__ in,
                                                  float* __restrict__ a_out,
                                                  float* __restrict__ d_out,
                                                  int Sin, int inStride,
                                                  int Lout, int outStride) {
    int row = blockIdx.y;
    int t = blockIdx.x * 256 + threadIdx.x;
    if (t >= Lout) return;
    const float* x = in + (size_t)row * inStride;
    float lo = 0.f, hi = 0.f;
#pragma unroll
    for (int k = 0; k < 16; ++k) {
        int i = 2 * t + k - 14;
        i = (i < 0) ? (-1 - i) : i;
        i = (i >= Sin) ? (2 * Sin - 1 - i) : i;
        float v = x[i];
        lo = fmaf(v, c_dlo[15 - k], lo);
        hi = fmaf(v, c_dhi[15 - k], hi);
    }
    a_out[(size_t)row * outStride + t] = lo;
    d_out[(size_t)row * outStride + t] = hi;
}

// ---------------- IDWT one level ----------------
__global__ __launch_bounds__(256) void idwt_kernel(const float* __restrict__ a,
                                                   const float* __restrict__ d,
                                                   float* __restrict__ out,
                                                   int Lc, int sA, int sD,
                                                   int Lout, int sOut) {
    int row = blockIdx.y;
    int t = blockIdx.x * 256 + threadIdx.x;
    if (t >= Lout) return;
    const float* ar = a + (size_t)row * sA;
    const float* dr = d + (size_t)row * sD;
    int m0 = t >> 1;
    float acc = 0.f;
    if ((t & 1) == 0) {
#pragma unroll
        for (int j = 0; j < 8; ++j) {
            int m = m0 + j;
            if (m < Lc) acc += ar[m] * c_dlo[2 * j + 1] + dr[m] * c_dlo[14 - 2 * j];
        }
    } else {
#pragma unroll
        for (int j = 0; j < 8; ++j) {
            int m = m0 + j;
            if (m < Lc) acc += ar[m] * c_dlo[2 * j] - dr[m] * c_dlo[15 - 2 * j];
        }
    }
    out[(size_t)row * sOut + t] = acc;
}

// ---------------- xo = h + gelu(xw + xs) ----------------
__global__ __launch_bounds__(256) void fuse_gelu_kernel(float* __restrict__ h,
                                                        const float* __restrict__ xw,
                                                        const float* __restrict__ xs) {
    int i = blockIdx.x * 256 + threadIdx.x;
    float u = xw[i] + xs[i];
    h[i] = h[i] + gelu1(u);
}

extern "C" void kernel_launch(void* const* d_in, const int* in_sizes, int n_in,
                              void* d_out, int out_size, void* d_ws, size_t ws_size,
                              hipStream_t stream) {
    const float* x       = (const float*)d_in[0];
    const float* lift_w  = (const float*)d_in[1];
    const float* lift_b  = (const float*)d_in[2];
    const float* blk_w_w = (const float*)d_in[3];
    const float* blk_w_b = (const float*)d_in[4];
    const float* blk_ca_w= (const float*)d_in[5];
    const float* blk_ca_b= (const float*)d_in[6];
    const float* blk_cd_w= (const float*)d_in[7];
    const float* blk_cd_b= (const float*)d_in[8];
    const float* blk_m1_w= (const float*)d_in[9];
    const float* blk_m1_b= (const float*)d_in[10];
    const float* blk_m2_w= (const float*)d_in[11];
    const float* blk_m2_b= (const float*)d_in[12];
    const float* p1_w    = (const float*)d_in[13];
    const float* p1_b    = (const float*)d_in[14];
    const float* p2_w    = (const float*)d_in[15];
    const float* p2_b    = (const float*)d_in[16];

    float* ws = (float*)d_ws;
    const size_t T32 = (size_t)NBC * S_LEN;
    float* A  = ws;                                  // h / xo
    float* Bb = ws + T32;                            // xn / xon / p1-out
    float* Cc = ws + 2 * T32;                        // xs
    float* Dd = ws + 3 * T32;                        // xw
    float* M  = Cc;                                  // MLP mid (B,128,S), aliases Cc+Dd
    float* d1 = ws + 4 * T32;
    float* d2 = d1 + (size_t)NBC * LP1;
    float* d3 = d2 + (size_t)NBC * LP2;
    float* d4 = d3 + (size_t)NBC * LP3;
    float* ap0 = d4 + (size_t)NBC * LP4;
    float* ap1 = ap0 + (size_t)NBC * 4104;

    dim3 blk(256);

    lift_kernel<<<(NBC * S_LEN) / 256, blk, 0, stream>>>(x, lift_w, lift_b, A);

    for (int i = 0; i < 4; ++i) {
        const float* w_w  = blk_w_w  + (size_t)i * 64 * 64 * 3;
        const float* w_b  = blk_w_b  + (size_t)i * 64;
        const float* ca_w = blk_ca_w + (size_t)i * 64 * 64;
        const float* ca_b = blk_ca_b + (size_t)i * 64;
        const float* cd_w = blk_cd_w + (size_t)i * 4 * 64 * 64;
        const float* cd_b = blk_cd_b + (size_t)i * 4 * 64;
        const float* m1_w = blk_m1_w + (size_t)i * 128 * 64;
        const float* m1_b = blk_m1_b + (size_t)i * 128;
        const float* m2_w = blk_m2_w + (size_t)i * 64 * 128;
        const float* m2_b = blk_m2_b + (size_t)i * 64;

        inorm_kernel<<<NBC, blk, 0, stream>>>(A, Bb);
        conv3_kernel<<<dim3(S_LEN / 256, B_N), blk, 0, stream>>>(Bb, Cc, w_w, w_b);

        dwt_kernel<<<dim3((L1v + 255) / 256, NBC), blk, 0, stream>>>(Bb,  ap0, d1, S_LEN, S_LEN, L1v, LP1);
        dwt_kernel<<<dim3((L2v + 255) / 256, NBC), blk, 0, stream>>>(ap0, ap1, d2, L1v, LP1, L2v, LP2);
        dwt_kernel<<<dim3((L3v + 255) / 256, NBC), blk, 0, stream>>>(ap1, ap0, d3, L2v, LP2, L3v, LP3);
        dwt_kernel<<<dim3((L4v + 255) / 256, NBC), blk, 0, stream>>>(ap0, ap1, d4, L3v, LP3, L4v, LP4);

        mix_kernel<64, 64, 8, 0, 0><<<dim3((L4v + 255) / 256, B_N), blk, 0, stream>>>(ap1, ap1, ca_w, ca_b, L4v, LP4);
        mix_kernel<64, 64, 8, 0, 0><<<dim3((L4v + 255) / 256, B_N), blk, 0, stream>>>(d4, d4, cd_w + 0 * 4096, cd_b + 0 * 64, L4v, LP4);
        mix_kernel<64, 64, 8, 0, 0><<<dim3((L3v + 255) / 256, B_N), blk, 0, stream>>>(d3, d3, cd_w + 1 * 4096, cd_b + 1 * 64, L3v, LP3);
        mix_kernel<64, 64, 8, 0, 0><<<dim3((L2v + 255) / 256, B_N), blk, 0, stream>>>(d2, d2, cd_w + 2 * 4096, cd_b + 2 * 64, L2v, LP2);
        mix_kernel<64, 64, 8, 0, 0><<<dim3((L1v + 255) / 256, B_N), blk, 0, stream>>>(d1, d1, cd_w + 3 * 4096, cd_b + 3 * 64, L1v, LP1);

        idwt_kernel<<<dim3((1038 + 255) / 256, NBC), blk, 0, stream>>>(ap1, d4, ap0, L4v, LP4, LP4, 1038, LP3);
        idwt_kernel<<<dim3((2060 + 255) / 256, NBC), blk, 0, stream>>>(ap0, d3, ap1, L3v, LP3, LP3, 2060, LP2);
        idwt_kernel<<<dim3((4104 + 255) / 256, NBC), blk, 0, stream>>>(ap1, d2, ap0, L2v, LP2, LP2, 4104, LP1);
        idwt_kernel<<<dim3((S_LEN + 255) / 256, NBC), blk, 0, stream>>>(ap0, d1, Dd, L1v, LP1, LP1, S_LEN, S_LEN);

        fuse_gelu_kernel<<<(NBC * S_LEN) / 256, blk, 0, stream>>>(A, Dd, Cc);

        inorm_kernel<<<NBC, blk, 0, stream>>>(A, Bb);
        mix_kernel<64, 128, 8, 1, 0><<<dim3(S_LEN / 128, B_N), blk, 0, stream>>>(Bb, M, m1_w, m1_b, S_LEN, S_LEN);
        mix_kernel<128, 64, 8, 0, 1><<<dim3(S_LEN / 256, B_N), blk, 0, stream>>>(M, A, m2_w, m2_b, S_LEN, S_LEN);
    }

    mix_kernel<64, 32, 4, 1, 0><<<dim3(S_LEN / 256, B_N), blk, 0, stream>>>(A, Bb, p1_w, p1_b, S_LEN, S_LEN);
    mix_kernel<32, 64, 8, 0, 0><<<dim3(S_LEN / 256, B_N), blk, 0, stream>>>(Bb, (float*)d_out, p2_w, p2_b, S_LEN, S_LEN);
}

// Round 3
// 1748.618 us; speedup vs baseline: 2.1130x; 1.2252x over previous
//
#include <hip/hip_runtime.h>
#include <math.h>

#define S_LEN 8192
#define B_N   16
#define NBC   1024          // B*C rows
#define L1v 4103
#define L2v 2059
#define L3v 1037
#define L4v 526
#define LP1 4104
#define LP2 2060
#define LP3 1040
#define LP4 528

__constant__ float c_dlo[16] = {
    -0.0033824159510061256f, -0.0005421323317911481f,  0.03169508781149298f,
     0.007607487324917605f,  -0.1432942383508097f,    -0.061273359067658524f,
     0.4813596512583722f,     0.7771857517005235f,     0.3644418948353314f,
    -0.05194583810770904f,   -0.027219029917056003f,   0.049137179673607506f,
     0.003808752013890615f,  -0.01495225833704823f,   -0.0003029205147213668f,
     0.0018899503327594609f
};
__constant__ float c_dhi[16] = {
    -0.0018899503327594609f, -0.0003029205147213668f,  0.01495225833704823f,
     0.003808752013890615f,  -0.049137179673607506f,  -0.027219029917056003f,
     0.05194583810770904f,    0.3644418948353314f,    -0.7771857517005235f,
     0.4813596512583722f,     0.061273359067658524f,  -0.1432942383508097f,
    -0.007607487324917605f,   0.03169508781149298f,    0.0005421323317911481f,
    -0.0033824159510061256f
};

__device__ __forceinline__ float gelu1(float x) {
    return 0.5f * x * (1.0f + erff(x * 0.70710678118654752f));
}
__device__ __forceinline__ float4 gelu4(float4 v) {
    v.x = gelu1(v.x); v.y = gelu1(v.y); v.z = gelu1(v.z); v.w = gelu1(v.w);
    return v;
}
__device__ __forceinline__ void fma4(float4& a, float w, const float4& x) {
    a.x = fmaf(w, x.x, a.x); a.y = fmaf(w, x.y, a.y);
    a.z = fmaf(w, x.z, a.z); a.w = fmaf(w, x.w, a.w);
}
__device__ __forceinline__ float4 load4g(const float* __restrict__ row, int l, int L) {
    float4 v;
    if (l >= 0 && l + 3 < L) {
        v = *(const float4*)(row + l);
    } else {
        v.x = (l     >= 0 && l     < L) ? row[l]     : 0.f;
        v.y = (l + 1 >= 0 && l + 1 < L) ? row[l + 1] : 0.f;
        v.z = (l + 2 >= 0 && l + 2 < L) ? row[l + 2] : 0.f;
        v.w = (l + 3 >= 0 && l + 3 < L) ? row[l + 3] : 0.f;
    }
    return v;
}
__device__ __forceinline__ void store4g(float* __restrict__ row, int l, int L, float4 v) {
    if (l + 3 < L) {
        *(float4*)(row + l) = v;
    } else {
        if (l     < L) row[l]     = v.x;
        if (l + 1 < L) row[l + 1] = v.y;
        if (l + 2 < L) row[l + 2] = v.z;
        if (l + 3 < L) row[l + 3] = v.w;
    }
}

// ---------------- lift ----------------
__global__ __launch_bounds__(256) void lift_kernel(const float* __restrict__ x,
                                                   const float* __restrict__ w,
                                                   const float* __restrict__ bias,
                                                   float* __restrict__ out) {
    int idx = blockIdx.x * 256 + threadIdx.x;
    int s = idx & (S_LEN - 1);
    int r = idx >> 13;
    int o = r & 63;
    int b = r >> 6;
    float g = -1.0f + 2.0f * (float)s / (float)(S_LEN - 1);
    out[idx] = fmaf(w[o * 2 + 0], x[b * S_LEN + s], fmaf(w[o * 2 + 1], g, bias[o]));
}

// ---------------- instance norm ----------------
__global__ __launch_bounds__(256) void inorm_kernel(const float* __restrict__ in,
                                                    float* __restrict__ out) {
    const int base = blockIdx.x * S_LEN;
    const int tid = threadIdx.x;
    float v[32];
    float s = 0.f, ss = 0.f;
#pragma unroll
    for (int i = 0; i < 32; ++i) {
        float xv = in[base + tid + i * 256];
        v[i] = xv;
        s += xv;
        ss = fmaf(xv, xv, ss);
    }
    for (int off = 32; off > 0; off >>= 1) {
        s  += __shfl_down(s, off, 64);
        ss += __shfl_down(ss, off, 64);
    }
    __shared__ float sh[8];
    int lane = tid & 63, wv = tid >> 6;
    if (lane == 0) { sh[wv] = s; sh[4 + wv] = ss; }
    __syncthreads();
    float tot  = sh[0] + sh[1] + sh[2] + sh[3];
    float tot2 = sh[4] + sh[5] + sh[6] + sh[7];
    float mean = tot * (1.0f / S_LEN);
    float var  = tot2 * (1.0f / S_LEN) - mean * mean;
    float inv  = rsqrtf(var + 1e-5f);
#pragma unroll
    for (int i = 0; i < 32; ++i)
        out[base + tid + i * 256] = (v[i] - mean) * inv;
}

// ---------------- conv1d k=3, C=64, LDS-staged weights, reg-blocked 8o x 8l ----------------
__device__ __forceinline__ void conv_fma(float4& acc, float w0, float w1, float w2,
                                         float xm, const float4& xv, float xp) {
    acc.x = fmaf(w0, xm,   fmaf(w1, xv.x, fmaf(w2, xv.y, acc.x)));
    acc.y = fmaf(w0, xv.x, fmaf(w1, xv.y, fmaf(w2, xv.z, acc.y)));
    acc.z = fmaf(w0, xv.y, fmaf(w1, xv.z, fmaf(w2, xv.w, acc.z)));
    acc.w = fmaf(w0, xv.z, fmaf(w1, xv.w, fmaf(w2, xp,   acc.w)));
}

__global__ __launch_bounds__(256) void conv3_kernel(const float* __restrict__ in,
                                                    float* __restrict__ out,
                                                    const float* __restrict__ W,   // (64,64,3)
                                                    const float* __restrict__ bias) {
    __shared__ float sx[32 * 264];   // 32 channels x [l0-4, l0+260)
    __shared__ float sw[32 * 192];   // [cc][k][o]
    const int b = blockIdx.y;
    const int l0 = blockIdx.x * 256;
    const int tid = threadIdx.x;
    const int og = tid >> 5;         // 0..7
    const int lg = tid & 31;         // 0..31

    float4 acc_a[8], acc_b[8];
#pragma unroll
    for (int j = 0; j < 8; ++j) {
        float bv = bias[og * 8 + j];
        acc_a[j] = make_float4(bv, bv, bv, bv);
        acc_b[j] = acc_a[j];
    }

    for (int ch = 0; ch < 2; ++ch) {
        const int c0 = ch * 32;
        if (ch) __syncthreads();
        for (int e = tid; e < 32 * 66; e += 256) {
            int cc = e / 66, p = e % 66;
            int l = l0 - 4 + p * 4;
            const float* row = in + ((size_t)(b * 64 + c0 + cc)) * S_LEN;
            *(float4*)(sx + cc * 264 + p * 4) = load4g(row, l, S_LEN);
        }
        for (int e = tid; e < 32 * 192; e += 256) {
            int cc = e / 192, r = e % 192;
            int k = r >> 6, o = r & 63;
            sw[cc * 192 + k * 64 + o] = W[o * 192 + (c0 + cc) * 3 + k];
        }
        __syncthreads();
#pragma unroll 2
        for (int cc = 0; cc < 32; ++cc) {
            const float* sxr = sx + cc * 264;
            const int ia = 4 + lg * 4;
            float  xm_a = sxr[ia - 1];
            float4 xva  = *(const float4*)(sxr + ia);
            float  xp_a = sxr[ia + 4];
            float  xm_b = sxr[ia + 127];
            float4 xvb  = *(const float4*)(sxr + ia + 128);
            float  xp_b = sxr[ia + 132];
            const float* swp = sw + cc * 192 + og * 8;
            float4 k0a = *(const float4*)(swp);
            float4 k0b = *(const float4*)(swp + 4);
            float4 k1a = *(const float4*)(swp + 64);
            float4 k1b = *(const float4*)(swp + 68);
            float4 k2a = *(const float4*)(swp + 128);
            float4 k2b = *(const float4*)(swp + 132);
            conv_fma(acc_a[0], k0a.x, k1a.x, k2a.x, xm_a, xva, xp_a);
            conv_fma(acc_b[0], k0a.x, k1a.x, k2a.x, xm_b, xvb, xp_b);
            conv_fma(acc_a[1], k0a.y, k1a.y, k2a.y, xm_a, xva, xp_a);
            conv_fma(acc_b[1], k0a.y, k1a.y, k2a.y, xm_b, xvb, xp_b);
            conv_fma(acc_a[2], k0a.z, k1a.z, k2a.z, xm_a, xva, xp_a);
            conv_fma(acc_b[2], k0a.z, k1a.z, k2a.z, xm_b, xvb, xp_b);
            conv_fma(acc_a[3], k0a.w, k1a.w, k2a.w, xm_a, xva, xp_a);
            conv_fma(acc_b[3], k0a.w, k1a.w, k2a.w, xm_b, xvb, xp_b);
            conv_fma(acc_a[4], k0b.x, k1b.x, k2b.x, xm_a, xva, xp_a);
            conv_fma(acc_b[4], k0b.x, k1b.x, k2b.x, xm_b, xvb, xp_b);
            conv_fma(acc_a[5], k0b.y, k1b.y, k2b.y, xm_a, xva, xp_a);
            conv_fma(acc_b[5], k0b.y, k1b.y, k2b.y, xm_b, xvb, xp_b);
            conv_fma(acc_a[6], k0b.z, k1b.z, k2b.z, xm_a, xva, xp_a);
            conv_fma(acc_b[6], k0b.z, k1b.z, k2b.z, xm_b, xvb, xp_b);
            conv_fma(acc_a[7], k0b.w, k1b.w, k2b.w, xm_a, xva, xp_a);
            conv_fma(acc_b[7], k0b.w, k1b.w, k2b.w, xm_b, xvb, xp_b);
        }
    }
#pragma unroll
    for (int j = 0; j < 8; ++j) {
        float* row = out + ((size_t)(b * 64 + og * 8 + j)) * S_LEN + l0;
        *(float4*)(row + lg * 4)       = acc_a[j];
        *(float4*)(row + 128 + lg * 4) = acc_b[j];
    }
}

// ---------------- channel mix GEMM ----------------
template <int CIN, int COUT, int TO, int ACT, int RES>
__global__ __launch_bounds__(256) void mix_kernel(const float* __restrict__ in,
                                                  float* __restrict__ out,
                                                  const float* __restrict__ W,
                                                  const float* __restrict__ bias,
                                                  int L, int LP) {
    constexpr int NOG = COUT / TO;
    constexpr int NLG = 256 / NOG;
    constexpr int LT  = NLG * 8;
    constexpr int KC  = (CIN < 32) ? CIN : 32;
    constexpr int NCH = CIN / KC;
    __shared__ float sx[KC * LT];
    __shared__ float sw[KC * COUT];
    const int b = blockIdx.y;
    const int l0 = blockIdx.x * LT;
    const int tid = threadIdx.x;
    const int og = tid / NLG;
    const int lg = tid % NLG;
    const int la = l0 + lg * 4;
    const int lb = la + NLG * 4;

    float4 acc_a[TO], acc_b[TO];
#pragma unroll
    for (int j = 0; j < TO; ++j) {
        float bv = bias[og * TO + j];
        acc_a[j] = make_float4(bv, bv, bv, bv);
        acc_b[j] = acc_a[j];
    }

    for (int ch = 0; ch < NCH; ++ch) {
        const int c0 = ch * KC;
        if (ch) __syncthreads();
        for (int e = tid; e < KC * LT / 4; e += 256) {
            const int cc = e / (LT / 4);
            const int p  = e % (LT / 4);
            const int l  = l0 + p * 4;
            const float* row = in + ((size_t)(b * CIN + c0 + cc)) * LP;
            *(float4*)(sx + cc * LT + p * 4) = load4g(row, l, L);
        }
        for (int e = tid; e < KC * COUT; e += 256) {
            const int cc = e / COUT;
            const int o  = e % COUT;
            sw[cc * COUT + o] = W[o * CIN + c0 + cc];
        }
        __syncthreads();
#pragma unroll 4
        for (int cc = 0; cc < KC; ++cc) {
            const float4 xa = *(const float4*)(sx + cc * LT + lg * 4);
            const float4 xb = *(const float4*)(sx + cc * LT + NLG * 4 + lg * 4);
            const float* swp = sw + cc * COUT + og * TO;
            const float4 w0 = *(const float4*)(swp);
            fma4(acc_a[0], w0.x, xa); fma4(acc_b[0], w0.x, xb);
            fma4(acc_a[1], w0.y, xa); fma4(acc_b[1], w0.y, xb);
            fma4(acc_a[2], w0.z, xa); fma4(acc_b[2], w0.z, xb);
            fma4(acc_a[3], w0.w, xa); fma4(acc_b[3], w0.w, xb);
            if constexpr (TO == 8) {
                const float4 w1 = *(const float4*)(swp + 4);
                fma4(acc_a[4], w1.x, xa); fma4(acc_b[4], w1.x, xb);
                fma4(acc_a[5], w1.y, xa); fma4(acc_b[5], w1.y, xb);
                fma4(acc_a[6], w1.z, xa); fma4(acc_b[6], w1.z, xb);
                fma4(acc_a[7], w1.w, xa); fma4(acc_b[7], w1.w, xb);
            }
        }
    }
#pragma unroll
    for (int j = 0; j < TO; ++j) {
        float* row = out + ((size_t)(b * COUT + og * TO + j)) * LP;
        float4 va = acc_a[j], vb = acc_b[j];
        if (ACT) { va = gelu4(va); vb = gelu4(vb); }
        if (RES) {
            float4 ra = load4g(row, la, L), rb = load4g(row, lb, L);
            va.x += ra.x; va.y += ra.y; va.z += ra.z; va.w += ra.w;
            vb.x += rb.x; vb.y += rb.y; vb.z += rb.z; vb.w += rb.w;
        }
        store4g(row, la, L, va);
        store4g(row, lb, L, vb);
    }
}

// ---------------- DWT one level: 8 outputs per thread, float4 loads ----------------
__global__ __launch_bounds__(256) void dwt_kernel(const float* __restrict__ in,
                                                  float* __restrict__ a_out,
                                                  float* __restrict__ d_out,
                                                  int Sin, int inStride,
                                                  int Lout, int outStride) {
    const int row = blockIdx.y;
    const int g = blockIdx.x * 256 + threadIdx.x;     // group of 8 outputs
    const int NT = (Lout + 7) >> 3;
    if (g >= NT) return;
    const float* x = in + (size_t)row * inStride;
    const int base = 16 * g - 16;                     // window [base, base+32)
    float xb[32];
    if (base >= 0 && base + 32 <= Sin) {
#pragma unroll
        for (int q = 0; q < 8; ++q)
            *(float4*)(xb + 4 * q) = *(const float4*)(x + base + 4 * q);
    } else {
#pragma unroll
        for (int loc = 0; loc < 32; ++loc) {
            int i = base + loc;
            i = (i < 0) ? (-1 - i) : i;
            i = (i >= Sin) ? (2 * Sin - 1 - i) : i;
            xb[loc] = x[i];
        }
    }
    float lo[8], hi[8];
#pragma unroll
    for (int j = 0; j < 8; ++j) {
        float l0 = 0.f, h0 = 0.f;
#pragma unroll
        for (int k = 0; k < 16; ++k) {
            float v = xb[2 * j + k + 2];
            l0 = fmaf(v, c_dlo[15 - k], l0);
            h0 = fmaf(v, c_dhi[15 - k], h0);
        }
        lo[j] = l0; hi[j] = h0;
    }
    float* ar = a_out + (size_t)row * outStride;
    float* dr = d_out + (size_t)row * outStride;
    const int t0 = 8 * g;
    store4g(ar, t0,     Lout, make_float4(lo[0], lo[1], lo[2], lo[3]));
    store4g(ar, t0 + 4, Lout, make_float4(lo[4], lo[5], lo[6], lo[7]));
    store4g(dr, t0,     Lout, make_float4(hi[0], hi[1], hi[2], hi[3]));
    store4g(dr, t0 + 4, Lout, make_float4(hi[4], hi[5], hi[6], hi[7]));
}

// ---------------- IDWT core: 8 outputs per thread from a/d windows ----------------
__device__ __forceinline__ void idwt8(const float* __restrict__ ar,
                                      const float* __restrict__ dr,
                                      int g, int Lc, float* __restrict__ y) {
    float av[12], dv[12];
    const int m0 = 4 * g;
    if (m0 + 12 <= Lc) {
#pragma unroll
        for (int q = 0; q < 3; ++q) {
            *(float4*)(av + 4 * q) = *(const float4*)(ar + m0 + 4 * q);
            *(float4*)(dv + 4 * q) = *(const float4*)(dr + m0 + 4 * q);
        }
    } else {
#pragma unroll
        for (int jj = 0; jj < 12; ++jj) {
            int m = m0 + jj;
            bool ok = (m < Lc);
            av[jj] = ok ? ar[m] : 0.f;
            dv[jj] = ok ? dr[m] : 0.f;
        }
    }
#pragma unroll
    for (int e = 0; e < 4; ++e) {
        float ye = 0.f, yo = 0.f;
#pragma unroll
        for (int j = 0; j < 8; ++j) {
            ye = fmaf(av[e + j], c_dlo[2 * j + 1], ye);
            ye = fmaf(dv[e + j], c_dlo[14 - 2 * j], ye);
            yo = fmaf(av[e + j], c_dlo[2 * j], yo);
            yo = fmaf(dv[e + j], -c_dlo[15 - 2 * j], yo);
        }
        y[2 * e] = ye;
        y[2 * e + 1] = yo;
    }
}

__global__ __launch_bounds__(256) void idwt_kernel(const float* __restrict__ a,
                                                   const float* __restrict__ d,
                                                   float* __restrict__ out,
                                                   int Lc, int sA, int sD,
                                                   int Lout, int sOut) {
    const int row = blockIdx.y;
    const int g = blockIdx.x * 256 + threadIdx.x;
    const int NT = (Lout + 7) >> 3;
    if (g >= NT) return;
    float y[8];
    idwt8(a + (size_t)row * sA, d + (size_t)row * sD, g, Lc, y);
    float* orow = out + (size_t)row * sOut;
    const int t0 = 8 * g;
    store4g(orow, t0,     Lout, make_float4(y[0], y[1], y[2], y[3]));
    store4g(orow, t0 + 4, Lout, make_float4(y[4], y[5], y[6], y[7]));
}

// ---------------- final IDWT fused with xo = h + gelu(xw + xs) ----------------
__global__ __launch_bounds__(256) void idwt_fuse_kernel(const float* __restrict__ a,
                                                        const float* __restrict__ d,
                                                        float* __restrict__ h,
                                                        const float* __restrict__ xs,
                                                        int Lc, int sA, int sD) {
    const int row = blockIdx.y;
    const int g = blockIdx.x * 256 + threadIdx.x;     // 1024 groups of 8 (Lout=8192)
    float y[8];
    idwt8(a + (size_t)row * sA, d + (size_t)row * sD, g, Lc, y);
    const size_t off = (size_t)row * S_LEN + 8 * g;
    float* hp = h + off;
    const float* sp = xs + off;
#pragma unroll
    for (int q = 0; q < 2; ++q) {
        float4 hv = *(const float4*)(hp + 4 * q);
        float4 sv = *(const float4*)(sp + 4 * q);
        hv.x += gelu1(y[4 * q + 0] + sv.x);
        hv.y += gelu1(y[4 * q + 1] + sv.y);
        hv.z += gelu1(y[4 * q + 2] + sv.z);
        hv.w += gelu1(y[4 * q + 3] + sv.w);
        *(float4*)(hp + 4 * q) = hv;
    }
}

extern "C" void kernel_launch(void* const* d_in, const int* in_sizes, int n_in,
                              void* d_out, int out_size, void* d_ws, size_t ws_size,
                              hipStream_t stream) {
    const float* x       = (const float*)d_in[0];
    const float* lift_w  = (const float*)d_in[1];
    const float* lift_b  = (const float*)d_in[2];
    const float* blk_w_w = (const float*)d_in[3];
    const float* blk_w_b = (const float*)d_in[4];
    const float* blk_ca_w= (const float*)d_in[5];
    const float* blk_ca_b= (const float*)d_in[6];
    const float* blk_cd_w= (const float*)d_in[7];
    const float* blk_cd_b= (const float*)d_in[8];
    const float* blk_m1_w= (const float*)d_in[9];
    const float* blk_m1_b= (const float*)d_in[10];
    const float* blk_m2_w= (const float*)d_in[11];
    const float* blk_m2_b= (const float*)d_in[12];
    const float* p1_w    = (const float*)d_in[13];
    const float* p1_b    = (const float*)d_in[14];
    const float* p2_w    = (const float*)d_in[15];
    const float* p2_b    = (const float*)d_in[16];

    float* ws = (float*)d_ws;
    const size_t T32 = (size_t)NBC * S_LEN;
    float* A  = ws;                                  // h / xo
    float* Bb = ws + T32;                            // xn / xon / p1-out
    float* Cc = ws + 2 * T32;                        // xs
    float* Dd = ws + 3 * T32;                        // (unused spare)
    float* M  = Cc;                                  // MLP mid (B,128,S), aliases Cc+Dd
    float* d1 = ws + 4 * T32;
    float* d2 = d1 + (size_t)NBC * LP1;
    float* d3 = d2 + (size_t)NBC * LP2;
    float* d4 = d3 + (size_t)NBC * LP3;
    float* ap0 = d4 + (size_t)NBC * LP4;
    float* ap1 = ap0 + (size_t)NBC * 4104;

    dim3 blk(256);

    lift_kernel<<<(NBC * S_LEN) / 256, blk, 0, stream>>>(x, lift_w, lift_b, A);

    for (int i = 0; i < 4; ++i) {
        const float* w_w  = blk_w_w  + (size_t)i * 64 * 64 * 3;
        const float* w_b  = blk_w_b  + (size_t)i * 64;
        const float* ca_w = blk_ca_w + (size_t)i * 64 * 64;
        const float* ca_b = blk_ca_b + (size_t)i * 64;
        const float* cd_w = blk_cd_w + (size_t)i * 4 * 64 * 64;
        const float* cd_b = blk_cd_b + (size_t)i * 4 * 64;
        const float* m1_w = blk_m1_w + (size_t)i * 128 * 64;
        const float* m1_b = blk_m1_b + (size_t)i * 128;
        const float* m2_w = blk_m2_w + (size_t)i * 64 * 128;
        const float* m2_b = blk_m2_b + (size_t)i * 64;

        inorm_kernel<<<NBC, blk, 0, stream>>>(A, Bb);
        conv3_kernel<<<dim3(S_LEN / 256, B_N), blk, 0, stream>>>(Bb, Cc, w_w, w_b);

        // DWT groups per level: ceil(Lout/8)
        dwt_kernel<<<dim3((((L1v + 7) / 8) + 255) / 256, NBC), blk, 0, stream>>>(Bb,  ap0, d1, S_LEN, S_LEN, L1v, LP1);
        dwt_kernel<<<dim3((((L2v + 7) / 8) + 255) / 256, NBC), blk, 0, stream>>>(ap0, ap1, d2, L1v, LP1, L2v, LP2);
        dwt_kernel<<<dim3((((L3v + 7) / 8) + 255) / 256, NBC), blk, 0, stream>>>(ap1, ap0, d3, L2v, LP2, L3v, LP3);
        dwt_kernel<<<dim3((((L4v + 7) / 8) + 255) / 256, NBC), blk, 0, stream>>>(ap0, ap1, d4, L3v, LP3, L4v, LP4);

        mix_kernel<64, 64, 8, 0, 0><<<dim3((L4v + 255) / 256, B_N), blk, 0, stream>>>(ap1, ap1, ca_w, ca_b, L4v, LP4);
        mix_kernel<64, 64, 8, 0, 0><<<dim3((L4v + 255) / 256, B_N), blk, 0, stream>>>(d4, d4, cd_w + 0 * 4096, cd_b + 0 * 64, L4v, LP4);
        mix_kernel<64, 64, 8, 0, 0><<<dim3((L3v + 255) / 256, B_N), blk, 0, stream>>>(d3, d3, cd_w + 1 * 4096, cd_b + 1 * 64, L3v, LP3);
        mix_kernel<64, 64, 8, 0, 0><<<dim3((L2v + 255) / 256, B_N), blk, 0, stream>>>(d2, d2, cd_w + 2 * 4096, cd_b + 2 * 64, L2v, LP2);
        mix_kernel<64, 64, 8, 0, 0><<<dim3((L1v + 255) / 256, B_N), blk, 0, stream>>>(d1, d1, cd_w + 3 * 4096, cd_b + 3 * 64, L1v, LP1);

        // waverec: 526->1038->2060->4104->8192 (a truncated to d length each step)
        idwt_kernel<<<dim3(((1038 / 8 + 1) + 255) / 256, NBC), blk, 0, stream>>>(ap1, d4, ap0, L4v, LP4, LP4, 1038, LP3);
        idwt_kernel<<<dim3(((2060 / 8 + 1) + 255) / 256, NBC), blk, 0, stream>>>(ap0, d3, ap1, L3v, LP3, LP3, 2060, LP2);
        idwt_kernel<<<dim3(((4104 / 8) + 255) / 256, NBC), blk, 0, stream>>>(ap1, d2, ap0, L2v, LP2, LP2, 4104, LP1);
        idwt_fuse_kernel<<<dim3((S_LEN / 8) / 256, NBC), blk, 0, stream>>>(ap0, d1, A, Cc, L1v, LP1, LP1);

        inorm_kernel<<<NBC, blk, 0, stream>>>(A, Bb);
        mix_kernel<64, 128, 8, 1, 0><<<dim3(S_LEN / 128, B_N), blk, 0, stream>>>(Bb, M, m1_w, m1_b, S_LEN, S_LEN);
        mix_kernel<128, 64, 8, 0, 1><<<dim3(S_LEN / 256, B_N), blk, 0, stream>>>(M, A, m2_w, m2_b, S_LEN, S_LEN);
    }

    mix_kernel<64, 32, 4, 1, 0><<<dim3(S_LEN / 256, B_N), blk, 0, stream>>>(A, Bb, p1_w, p1_b, S_LEN, S_LEN);
    mix_kernel<32, 64, 8, 0, 0><<<dim3(S_LEN / 256, B_N), blk, 0, stream>>>(Bb, (float*)d_out, p2_w, p2_b, S_LEN, S_LEN);
}

// Round 4
// 1496.938 us; speedup vs baseline: 2.4683x; 1.1681x over previous
//
#include <hip/hip_runtime.h>
#include <math.h>

#define S_LEN 8192
#define B_N   16
#define NBC   1024          // B*C rows
#define L1v 4103
#define L2v 2059
#define L3v 1037
#define L4v 526
#define LP1 4104
#define LP2 2060
#define LP3 1040
#define LP4 528

typedef __attribute__((ext_vector_type(8))) short bf16x8;
typedef __attribute__((ext_vector_type(4))) float f32x4;

__constant__ float c_dlo[16] = {
    -0.0033824159510061256f, -0.0005421323317911481f,  0.03169508781149298f,
     0.007607487324917605f,  -0.1432942383508097f,    -0.061273359067658524f,
     0.4813596512583722f,     0.7771857517005235f,     0.3644418948353314f,
    -0.05194583810770904f,   -0.027219029917056003f,   0.049137179673607506f,
     0.003808752013890615f,  -0.01495225833704823f,   -0.0003029205147213668f,
     0.0018899503327594609f
};
__constant__ float c_dhi[16] = {
    -0.0018899503327594609f, -0.0003029205147213668f,  0.01495225833704823f,
     0.003808752013890615f,  -0.049137179673607506f,  -0.027219029917056003f,
     0.05194583810770904f,    0.3644418948353314f,    -0.7771857517005235f,
     0.4813596512583722f,     0.061273359067658524f,  -0.1432942383508097f,
    -0.007607487324917605f,   0.03169508781149298f,    0.0005421323317911481f,
    -0.0033824159510061256f
};

__device__ __forceinline__ float gelu1(float x) {
    return 0.5f * x * (1.0f + erff(x * 0.70710678118654752f));
}
__device__ __forceinline__ float4 gelu4(float4 v) {
    v.x = gelu1(v.x); v.y = gelu1(v.y); v.z = gelu1(v.z); v.w = gelu1(v.w);
    return v;
}
__device__ __forceinline__ void fma4(float4& a, float w, const float4& x) {
    a.x = fmaf(w, x.x, a.x); a.y = fmaf(w, x.y, a.y);
    a.z = fmaf(w, x.z, a.z); a.w = fmaf(w, x.w, a.w);
}
__device__ __forceinline__ float4 load4g(const float* __restrict__ row, int l, int L) {
    float4 v;
    if (l >= 0 && l + 3 < L) {
        v = *(const float4*)(row + l);
    } else {
        v.x = (l     >= 0 && l     < L) ? row[l]     : 0.f;
        v.y = (l + 1 >= 0 && l + 1 < L) ? row[l + 1] : 0.f;
        v.z = (l + 2 >= 0 && l + 2 < L) ? row[l + 2] : 0.f;
        v.w = (l + 3 >= 0 && l + 3 < L) ? row[l + 3] : 0.f;
    }
    return v;
}
__device__ __forceinline__ void store4g(float* __restrict__ row, int l, int L, float4 v) {
    if (l + 3 < L) {
        *(float4*)(row + l) = v;
    } else {
        if (l     < L) row[l]     = v.x;
        if (l + 1 < L) row[l + 1] = v.y;
        if (l + 2 < L) row[l + 2] = v.z;
        if (l + 3 < L) row[l + 3] = v.w;
    }
}
__device__ __forceinline__ ushort f2bf(float f) {
    uint u = __float_as_uint(f);
    u += 0x7fffu + ((u >> 16) & 1u);
    return (ushort)(u >> 16);
}
__device__ __forceinline__ uint pack2bf(float a, float b) {
    return (uint)f2bf(a) | ((uint)f2bf(b) << 16);
}

// ---------------- lift ----------------
__global__ __launch_bounds__(256) void lift_kernel(const float* __restrict__ x,
                                                   const float* __restrict__ w,
                                                   const float* __restrict__ bias,
                                                   float* __restrict__ out) {
    int idx = blockIdx.x * 256 + threadIdx.x;
    int s = idx & (S_LEN - 1);
    int r = idx >> 13;
    int o = r & 63;
    int b = r >> 6;
    float g = -1.0f + 2.0f * (float)s / (float)(S_LEN - 1);
    out[idx] = fmaf(w[o * 2 + 0], x[b * S_LEN + s], fmaf(w[o * 2 + 1], g, bias[o]));
}

// ---------------- row stats: mean + rsqrt(var+eps) ----------------
__global__ __launch_bounds__(256) void stats_kernel(const float* __restrict__ in,
                                                    float2* __restrict__ stats) {
    const int base = blockIdx.x * S_LEN;
    const int tid = threadIdx.x;
    float s = 0.f, ss = 0.f;
#pragma unroll
    for (int i = 0; i < 8; ++i) {
        float4 v = *(const float4*)(in + base + (tid + i * 256) * 4);
        s += v.x + v.y + v.z + v.w;
        ss = fmaf(v.x, v.x, fmaf(v.y, v.y, fmaf(v.z, v.z, fmaf(v.w, v.w, ss))));
    }
    for (int off = 32; off > 0; off >>= 1) {
        s  += __shfl_down(s, off, 64);
        ss += __shfl_down(ss, off, 64);
    }
    __shared__ float sh[8];
    int lane = tid & 63, wv = tid >> 6;
    if (lane == 0) { sh[wv] = s; sh[4 + wv] = ss; }
    __syncthreads();
    if (tid == 0) {
        float tot  = sh[0] + sh[1] + sh[2] + sh[3];
        float tot2 = sh[4] + sh[5] + sh[6] + sh[7];
        float mean = tot * (1.0f / S_LEN);
        float var  = tot2 * (1.0f / S_LEN) - mean * mean;
        stats[blockIdx.x] = make_float2(mean, rsqrtf(var + 1e-5f));
    }
}

// ---------------- conv1d k=3, normalizes input on the fly ----------------
__device__ __forceinline__ void conv_fma(float4& acc, float w0, float w1, float w2,
                                         float xm, const float4& xv, float xp) {
    acc.x = fmaf(w0, xm,   fmaf(w1, xv.x, fmaf(w2, xv.y, acc.x)));
    acc.y = fmaf(w0, xv.x, fmaf(w1, xv.y, fmaf(w2, xv.z, acc.y)));
    acc.z = fmaf(w0, xv.y, fmaf(w1, xv.z, fmaf(w2, xv.w, acc.z)));
    acc.w = fmaf(w0, xv.z, fmaf(w1, xv.w, fmaf(w2, xp,   acc.w)));
}

__global__ __launch_bounds__(256) void conv3_kernel(const float* __restrict__ in,
                                                    float* __restrict__ out,
                                                    const float* __restrict__ W,   // (64,64,3)
                                                    const float* __restrict__ bias,
                                                    const float2* __restrict__ stats) {
    __shared__ float sx[32 * 264];
    __shared__ float sw[32 * 192];
    const int b = blockIdx.y;
    const int l0 = blockIdx.x * 256;
    const int tid = threadIdx.x;
    const int og = tid >> 5;
    const int lg = tid & 31;

    float4 acc_a[8], acc_b[8];
#pragma unroll
    for (int j = 0; j < 8; ++j) {
        float bv = bias[og * 8 + j];
        acc_a[j] = make_float4(bv, bv, bv, bv);
        acc_b[j] = acc_a[j];
    }

    for (int ch = 0; ch < 2; ++ch) {
        const int c0 = ch * 32;
        if (ch) __syncthreads();
        for (int e = tid; e < 32 * 66; e += 256) {
            int cc = e / 66, p = e % 66;
            int l = l0 - 4 + p * 4;
            const int rowi = b * 64 + c0 + cc;
            const float* row = in + (size_t)rowi * S_LEN;
            float2 st = stats[rowi];
            float4 v;
            if (l >= 0 && l + 3 < S_LEN) {
                v = *(const float4*)(row + l);
                v.x = (v.x - st.x) * st.y; v.y = (v.y - st.x) * st.y;
                v.z = (v.z - st.x) * st.y; v.w = (v.w - st.x) * st.y;
            } else {
                v.x = (l     >= 0 && l     < S_LEN) ? (row[l]     - st.x) * st.y : 0.f;
                v.y = (l + 1 >= 0 && l + 1 < S_LEN) ? (row[l + 1] - st.x) * st.y : 0.f;
                v.z = (l + 2 >= 0 && l + 2 < S_LEN) ? (row[l + 2] - st.x) * st.y : 0.f;
                v.w = (l + 3 >= 0 && l + 3 < S_LEN) ? (row[l + 3] - st.x) * st.y : 0.f;
            }
            *(float4*)(sx + cc * 264 + p * 4) = v;
        }
        for (int e = tid; e < 32 * 192; e += 256) {
            int cc = e / 192, r = e % 192;
            int k = r >> 6, o = r & 63;
            sw[cc * 192 + k * 64 + o] = W[o * 192 + (c0 + cc) * 3 + k];
        }
        __syncthreads();
#pragma unroll 2
        for (int cc = 0; cc < 32; ++cc) {
            const float* sxr = sx + cc * 264;
            const int ia = 4 + lg * 4;
            float  xm_a = sxr[ia - 1];
            float4 xva  = *(const float4*)(sxr + ia);
            float  xp_a = sxr[ia + 4];
            float  xm_b = sxr[ia + 127];
            float4 xvb  = *(const float4*)(sxr + ia + 128);
            float  xp_b = sxr[ia + 132];
            const float* swp = sw + cc * 192 + og * 8;
            float4 k0a = *(const float4*)(swp);
            float4 k0b = *(const float4*)(swp + 4);
            float4 k1a = *(const float4*)(swp + 64);
            float4 k1b = *(const float4*)(swp + 68);
            float4 k2a = *(const float4*)(swp + 128);
            float4 k2b = *(const float4*)(swp + 132);
            conv_fma(acc_a[0], k0a.x, k1a.x, k2a.x, xm_a, xva, xp_a);
            conv_fma(acc_b[0], k0a.x, k1a.x, k2a.x, xm_b, xvb, xp_b);
            conv_fma(acc_a[1], k0a.y, k1a.y, k2a.y, xm_a, xva, xp_a);
            conv_fma(acc_b[1], k0a.y, k1a.y, k2a.y, xm_b, xvb, xp_b);
            conv_fma(acc_a[2], k0a.z, k1a.z, k2a.z, xm_a, xva, xp_a);
            conv_fma(acc_b[2], k0a.z, k1a.z, k2a.z, xm_b, xvb, xp_b);
            conv_fma(acc_a[3], k0a.w, k1a.w, k2a.w, xm_a, xva, xp_a);
            conv_fma(acc_b[3], k0a.w, k1a.w, k2a.w, xm_b, xvb, xp_b);
            conv_fma(acc_a[4], k0b.x, k1b.x, k2b.x, xm_a, xva, xp_a);
            conv_fma(acc_b[4], k0b.x, k1b.x, k2b.x, xm_b, xvb, xp_b);
            conv_fma(acc_a[5], k0b.y, k1b.y, k2b.y, xm_a, xva, xp_a);
            conv_fma(acc_b[5], k0b.y, k1b.y, k2b.y, xm_b, xvb, xp_b);
            conv_fma(acc_a[6], k0b.z, k1b.z, k2b.z, xm_a, xva, xp_a);
            conv_fma(acc_b[6], k0b.z, k1b.z, k2b.z, xm_b, xvb, xp_b);
            conv_fma(acc_a[7], k0b.w, k1b.w, k2b.w, xm_a, xva, xp_a);
            conv_fma(acc_b[7], k0b.w, k1b.w, k2b.w, xm_b, xvb, xp_b);
        }
    }
#pragma unroll
    for (int j = 0; j < 8; ++j) {
        float* row = out + ((size_t)(b * 64 + og * 8 + j)) * S_LEN + l0;
        *(float4*)(row + lg * 4)       = acc_a[j];
        *(float4*)(row + 128 + lg * 4) = acc_b[j];
    }
}

// ---------------- channel mix GEMM (f32, wavelet-domain + head) ----------------
template <int CIN, int COUT, int TO, int ACT, int RES>
__global__ __launch_bounds__(256) void mix_kernel(const float* __restrict__ in,
                                                  float* __restrict__ out,
                                                  const float* __restrict__ W,
                                                  const float* __restrict__ bias,
                                                  int L, int LP) {
    constexpr int NOG = COUT / TO;
    constexpr int NLG = 256 / NOG;
    constexpr int LT  = NLG * 8;
    constexpr int KC  = (CIN < 32) ? CIN : 32;
    constexpr int NCH = CIN / KC;
    __shared__ float sx[KC * LT];
    __shared__ float sw[KC * COUT];
    const int b = blockIdx.y;
    const int l0 = blockIdx.x * LT;
    const int tid = threadIdx.x;
    const int og = tid / NLG;
    const int lg = tid % NLG;
    const int la = l0 + lg * 4;
    const int lb = la + NLG * 4;

    float4 acc_a[TO], acc_b[TO];
#pragma unroll
    for (int j = 0; j < TO; ++j) {
        float bv = bias[og * TO + j];
        acc_a[j] = make_float4(bv, bv, bv, bv);
        acc_b[j] = acc_a[j];
    }

    for (int ch = 0; ch < NCH; ++ch) {
        const int c0 = ch * KC;
        if (ch) __syncthreads();
        for (int e = tid; e < KC * LT / 4; e += 256) {
            const int cc = e / (LT / 4);
            const int p  = e % (LT / 4);
            const int l  = l0 + p * 4;
            const float* row = in + ((size_t)(b * CIN + c0 + cc)) * LP;
            *(float4*)(sx + cc * LT + p * 4) = load4g(row, l, L);
        }
        for (int e = tid; e < KC * COUT; e += 256) {
            const int cc = e / COUT;
            const int o  = e % COUT;
            sw[cc * COUT + o] = W[o * CIN + c0 + cc];
        }
        __syncthreads();
#pragma unroll 4
        for (int cc = 0; cc < KC; ++cc) {
            const float4 xa = *(const float4*)(sx + cc * LT + lg * 4);
            const float4 xb = *(const float4*)(sx + cc * LT + NLG * 4 + lg * 4);
            const float* swp = sw + cc * COUT + og * TO;
            const float4 w0 = *(const float4*)(swp);
            fma4(acc_a[0], w0.x, xa); fma4(acc_b[0], w0.x, xb);
            fma4(acc_a[1], w0.y, xa); fma4(acc_b[1], w0.y, xb);
            fma4(acc_a[2], w0.z, xa); fma4(acc_b[2], w0.z, xb);
            fma4(acc_a[3], w0.w, xa); fma4(acc_b[3], w0.w, xb);
            if constexpr (TO == 8) {
                const float4 w1 = *(const float4*)(swp + 4);
                fma4(acc_a[4], w1.x, xa); fma4(acc_b[4], w1.x, xb);
                fma4(acc_a[5], w1.y, xa); fma4(acc_b[5], w1.y, xb);
                fma4(acc_a[6], w1.z, xa); fma4(acc_b[6], w1.z, xb);
                fma4(acc_a[7], w1.w, xa); fma4(acc_b[7], w1.w, xb);
            }
        }
    }
#pragma unroll
    for (int j = 0; j < TO; ++j) {
        float* row = out + ((size_t)(b * COUT + og * TO + j)) * LP;
        float4 va = acc_a[j], vb = acc_b[j];
        if (ACT) { va = gelu4(va); vb = gelu4(vb); }
        if (RES) {
            float4 ra = load4g(row, la, L), rb = load4g(row, lb, L);
            va.x += ra.x; va.y += ra.y; va.z += ra.z; va.w += ra.w;
            vb.x += rb.x; vb.y += rb.y; vb.z += rb.z; vb.w += rb.w;
        }
        store4g(row, la, L, va);
        store4g(row, lb, L, vb);
    }
}

// ---------------- fused MLP: A += W2 * gelu(W1 * inorm(A) + b1) + b2 (bf16 MFMA) ----------
#define W1P 72
#define W2P 136
#define XP  66
#define MP  136

__global__ __launch_bounds__(256) void mlp_kernel(float* __restrict__ A,
                                                  const float2* __restrict__ stats,
                                                  const float* __restrict__ W1,
                                                  const float* __restrict__ b1,
                                                  const float* __restrict__ W2,
                                                  const float* __restrict__ b2) {
    __shared__ ushort sW1[128 * W1P];
    __shared__ ushort sW2[64 * W2P];
    __shared__ ushort sX [64 * XP];
    __shared__ ushort sMid[64 * MP];
    const int b  = blockIdx.y;
    const int n0 = blockIdx.x * 64;
    const int tid = threadIdx.x;

    {   // stage W1 (128x64) -> bf16 [m][k]
        int row = tid >> 1, half = tid & 1;
        const float* src = W1 + row * 64 + half * 32;
        uint* dst = (uint*)(sW1 + row * W1P + half * 32);
#pragma unroll
        for (int i = 0; i < 8; ++i) {
            float4 v = *(const float4*)(src + 4 * i);
            dst[2 * i]     = pack2bf(v.x, v.y);
            dst[2 * i + 1] = pack2bf(v.z, v.w);
        }
    }
    {   // stage W2 (64x128) -> bf16 [m][k]
        int row = tid >> 2, q = tid & 3;
        const float* src = W2 + row * 128 + q * 32;
        uint* dst = (uint*)(sW2 + row * W2P + q * 32);
#pragma unroll
        for (int i = 0; i < 8; ++i) {
            float4 v = *(const float4*)(src + 4 * i);
            dst[2 * i]     = pack2bf(v.x, v.y);
            dst[2 * i + 1] = pack2bf(v.z, v.w);
        }
    }
    {   // stage xn tile: normalize A[ch][n0..n0+63] -> bf16 [ch][pos]
        int ch = tid >> 2, part = tid & 3;
        float2 st = stats[b * 64 + ch];
        const float* src = A + ((size_t)(b * 64 + ch)) * S_LEN + n0 + part * 16;
        uint* dst = (uint*)(sX + ch * XP + part * 16);
#pragma unroll
        for (int i = 0; i < 4; ++i) {
            float4 v = *(const float4*)(src + 4 * i);
            v.x = (v.x - st.x) * st.y; v.y = (v.y - st.x) * st.y;
            v.z = (v.z - st.x) * st.y; v.w = (v.w - st.x) * st.y;
            dst[2 * i]     = pack2bf(v.x, v.y);
            dst[2 * i + 1] = pack2bf(v.z, v.w);
        }
    }
    __syncthreads();

    const int w = tid >> 6;          // wave id = n-subtile (16 positions)
    const int l = tid & 63;
    const int g = l >> 4;
    const int c = l & 15;
    const int nl = 16 * w + c;       // local position

    // B fragments for GEMM1 (k = input channel, 0..63)
    bf16x8 xb[2];
#pragma unroll
    for (int kk = 0; kk < 2; ++kk)
#pragma unroll
        for (int j = 0; j < 8; ++j)
            xb[kk][j] = (short)sX[(kk * 32 + 8 * g + j) * XP + nl];

    // GEMM1: mid[m=0..127][nl]
    f32x4 acc1[8];
#pragma unroll
    for (int mt = 0; mt < 8; ++mt) {
        float4 bv = *(const float4*)(b1 + 16 * mt + 4 * g);
        acc1[mt][0] = bv.x; acc1[mt][1] = bv.y; acc1[mt][2] = bv.z; acc1[mt][3] = bv.w;
    }
#pragma unroll
    for (int kk = 0; kk < 2; ++kk) {
#pragma unroll
        for (int mt = 0; mt < 8; ++mt) {
            bf16x8 af = *(bf16x8*)(sW1 + (16 * mt + c) * W1P + kk * 32 + 8 * g);
            acc1[mt] = __builtin_amdgcn_mfma_f32_16x16x32_bf16(af, xb[kk], acc1[mt], 0, 0, 0);
        }
    }
    // gelu -> bf16 -> sMid [pos][midch] (wave-private rows, no barrier needed)
#pragma unroll
    for (int mt = 0; mt < 8; ++mt)
#pragma unroll
        for (int r = 0; r < 4; ++r)
            sMid[nl * MP + 16 * mt + 4 * g + r] = f2bf(gelu1(acc1[mt][r]));

    // GEMM2: out[m=0..63][nl], K = 128
    bf16x8 mb[4];
#pragma unroll
    for (int kk = 0; kk < 4; ++kk)
        mb[kk] = *(bf16x8*)(sMid + nl * MP + kk * 32 + 8 * g);

    f32x4 acc2[4];
#pragma unroll
    for (int mt = 0; mt < 4; ++mt) {
        float4 bv = *(const float4*)(b2 + 16 * mt + 4 * g);
        acc2[mt][0] = bv.x; acc2[mt][1] = bv.y; acc2[mt][2] = bv.z; acc2[mt][3] = bv.w;
    }
#pragma unroll
    for (int kk = 0; kk < 4; ++kk) {
#pragma unroll
        for (int mt = 0; mt < 4; ++mt) {
            bf16x8 af = *(bf16x8*)(sW2 + (16 * mt + c) * W2P + kk * 32 + 8 * g);
            acc2[mt] = __builtin_amdgcn_mfma_f32_16x16x32_bf16(af, mb[kk], acc2[mt], 0, 0, 0);
        }
    }
    // epilogue: residual add, store
#pragma unroll
    for (int mt = 0; mt < 4; ++mt) {
#pragma unroll
        for (int r = 0; r < 4; ++r) {
            int m = 16 * mt + 4 * g + r;
            float* p = A + ((size_t)(b * 64 + m)) * S_LEN + n0 + nl;
            *p = acc2[mt][r] + *p;
        }
    }
}

// ---------------- DWT one level (optional on-the-fly inorm) ----------------
__global__ __launch_bounds__(256) void dwt_kernel(const float* __restrict__ in,
                                                  float* __restrict__ a_out,
                                                  float* __restrict__ d_out,
                                                  const float2* __restrict__ st,
                                                  int Sin, int inStride,
                                                  int Lout, int outStride) {
    const int row = blockIdx.y;
    const int g = blockIdx.x * 256 + threadIdx.x;
    const int NT = (Lout + 7) >> 3;
    if (g >= NT) return;
    float mean = 0.f, inv = 1.f;
    if (st) { float2 s2 = st[row]; mean = s2.x; inv = s2.y; }
    const float* x = in + (size_t)row * inStride;
    const int base = 16 * g - 16;
    float xb[32];
    if (base >= 0 && base + 32 <= Sin) {
#pragma unroll
        for (int q = 0; q < 8; ++q)
            *(float4*)(xb + 4 * q) = *(const float4*)(x + base + 4 * q);
    } else {
#pragma unroll
        for (int loc = 0; loc < 32; ++loc) {
            int i = base + loc;
            i = (i < 0) ? (-1 - i) : i;
            i = (i >= Sin) ? (2 * Sin - 1 - i) : i;
            xb[loc] = x[i];
        }
    }
    if (st) {
#pragma unroll
        for (int loc = 0; loc < 32; ++loc) xb[loc] = (xb[loc] - mean) * inv;
    }
    float lo[8], hi[8];
#pragma unroll
    for (int j = 0; j < 8; ++j) {
        float l0 = 0.f, h0 = 0.f;
#pragma unroll
        for (int k = 0; k < 16; ++k) {
            float v = xb[2 * j + k + 2];
            l0 = fmaf(v, c_dlo[15 - k], l0);
            h0 = fmaf(v, c_dhi[15 - k], h0);
        }
        lo[j] = l0; hi[j] = h0;
    }
    float* ar = a_out + (size_t)row * outStride;
    float* dr = d_out + (size_t)row * outStride;
    const int t0 = 8 * g;
    store4g(ar, t0,     Lout, make_float4(lo[0], lo[1], lo[2], lo[3]));
    store4g(ar, t0 + 4, Lout, make_float4(lo[4], lo[5], lo[6], lo[7]));
    store4g(dr, t0,     Lout, make_float4(hi[0], hi[1], hi[2], hi[3]));
    store4g(dr, t0 + 4, Lout, make_float4(hi[4], hi[5], hi[6], hi[7]));
}

// ---------------- IDWT core ----------------
__device__ __forceinline__ void idwt8(const float* __restrict__ ar,
                                      const float* __restrict__ dr,
                                      int g, int Lc, float* __restrict__ y) {
    float av[12], dv[12];
    const int m0 = 4 * g;
    if (m0 + 12 <= Lc) {
#pragma unroll
        for (int q = 0; q < 3; ++q) {
            *(float4*)(av + 4 * q) = *(const float4*)(ar + m0 + 4 * q);
            *(float4*)(dv + 4 * q) = *(const float4*)(dr + m0 + 4 * q);
        }
    } else {
#pragma unroll
        for (int jj = 0; jj < 12; ++jj) {
            int m = m0 + jj;
            bool ok = (m < Lc);
            av[jj] = ok ? ar[m] : 0.f;
            dv[jj] = ok ? dr[m] : 0.f;
        }
    }
#pragma unroll
    for (int e = 0; e < 4; ++e) {
        float ye = 0.f, yo = 0.f;
#pragma unroll
        for (int j = 0; j < 8; ++j) {
            ye = fmaf(av[e + j], c_dlo[2 * j + 1], ye);
            ye = fmaf(dv[e + j], c_dlo[14 - 2 * j], ye);
            yo = fmaf(av[e + j], c_dlo[2 * j], yo);
            yo = fmaf(dv[e + j], -c_dlo[15 - 2 * j], yo);
        }
        y[2 * e] = ye;
        y[2 * e + 1] = yo;
    }
}

__global__ __launch_bounds__(256) void idwt_kernel(const float* __restrict__ a,
                                                   const float* __restrict__ d,
                                                   float* __restrict__ out,
                                                   int Lc, int sA, int sD,
                                                   int Lout, int sOut) {
    const int row = blockIdx.y;
    const int g = blockIdx.x * 256 + threadIdx.x;
    const int NT = (Lout + 7) >> 3;
    if (g >= NT) return;
    float y[8];
    idwt8(a + (size_t)row * sA, d + (size_t)row * sD, g, Lc, y);
    float* orow = out + (size_t)row * sOut;
    const int t0 = 8 * g;
    store4g(orow, t0,     Lout, make_float4(y[0], y[1], y[2], y[3]));
    store4g(orow, t0 + 4, Lout, make_float4(y[4], y[5], y[6], y[7]));
}

// ---------------- final IDWT fused with xo = h + gelu(xw + xs) ----------------
__global__ __launch_bounds__(256) void idwt_fuse_kernel(const float* __restrict__ a,
                                                        const float* __restrict__ d,
                                                        float* __restrict__ h,
                                                        const float* __restrict__ xs,
                                                        int Lc, int sA, int sD) {
    const int row = blockIdx.y;
    const int g = blockIdx.x * 256 + threadIdx.x;
    float y[8];
    idwt8(a + (size_t)row * sA, d + (size_t)row * sD, g, Lc, y);
    const size_t off = (size_t)row * S_LEN + 8 * g;
    float* hp = h + off;
    const float* sp = xs + off;
#pragma unroll
    for (int q = 0; q < 2; ++q) {
        float4 hv = *(const float4*)(hp + 4 * q);
        float4 sv = *(const float4*)(sp + 4 * q);
        hv.x += gelu1(y[4 * q + 0] + sv.x);
        hv.y += gelu1(y[4 * q + 1] + sv.y);
        hv.z += gelu1(y[4 * q + 2] + sv.z);
        hv.w += gelu1(y[4 * q + 3] + sv.w);
        *(float4*)(hp + 4 * q) = hv;
    }
}

extern "C" void kernel_launch(void* const* d_in, const int* in_sizes, int n_in,
                              void* d_out, int out_size, void* d_ws, size_t ws_size,
                              hipStream_t stream) {
    const float* x       = (const float*)d_in[0];
    const float* lift_w  = (const float*)d_in[1];
    const float* lift_b  = (const float*)d_in[2];
    const float* blk_w_w = (const float*)d_in[3];
    const float* blk_w_b = (const float*)d_in[4];
    const float* blk_ca_w= (const float*)d_in[5];
    const float* blk_ca_b= (const float*)d_in[6];
    const float* blk_cd_w= (const float*)d_in[7];
    const float* blk_cd_b= (const float*)d_in[8];
    const float* blk_m1_w= (const float*)d_in[9];
    const float* blk_m1_b= (const float*)d_in[10];
    const float* blk_m2_w= (const float*)d_in[11];
    const float* blk_m2_b= (const float*)d_in[12];
    const float* p1_w    = (const float*)d_in[13];
    const float* p1_b    = (const float*)d_in[14];
    const float* p2_w    = (const float*)d_in[15];
    const float* p2_b    = (const float*)d_in[16];

    float* ws = (float*)d_ws;
    const size_t T32 = (size_t)NBC * S_LEN;
    float* A  = ws;                                  // h / xo (residual stream)
    float* Bb = ws + T32;                            // head p1 output
    float* Cc = ws + 2 * T32;                        // xs (conv out)
    float* d1 = ws + 4 * T32;
    float* d2 = d1 + (size_t)NBC * LP1;
    float* d3 = d2 + (size_t)NBC * LP2;
    float* d4 = d3 + (size_t)NBC * LP3;
    float* ap0 = d4 + (size_t)NBC * LP4;
    float* ap1 = ap0 + (size_t)NBC * 4104;
    float2* statsBuf = (float2*)(ap1 + (size_t)NBC * 4104);

    dim3 blk(256);

    lift_kernel<<<(NBC * S_LEN) / 256, blk, 0, stream>>>(x, lift_w, lift_b, A);

    for (int i = 0; i < 4; ++i) {
        const float* w_w  = blk_w_w  + (size_t)i * 64 * 64 * 3;
        const float* w_b  = blk_w_b  + (size_t)i * 64;
        const float* ca_w = blk_ca_w + (size_t)i * 64 * 64;
        const float* ca_b = blk_ca_b + (size_t)i * 64;
        const float* cd_w = blk_cd_w + (size_t)i * 4 * 64 * 64;
        const float* cd_b = blk_cd_b + (size_t)i * 4 * 64;
        const float* m1_w = blk_m1_w + (size_t)i * 128 * 64;
        const float* m1_b = blk_m1_b + (size_t)i * 128;
        const float* m2_w = blk_m2_w + (size_t)i * 64 * 128;
        const float* m2_b = blk_m2_b + (size_t)i * 64;

        stats_kernel<<<NBC, blk, 0, stream>>>(A, statsBuf);
        conv3_kernel<<<dim3(S_LEN / 256, B_N), blk, 0, stream>>>(A, Cc, w_w, w_b, statsBuf);

        dwt_kernel<<<dim3((((L1v + 7) / 8) + 255) / 256, NBC), blk, 0, stream>>>(A,   ap0, d1, statsBuf, S_LEN, S_LEN, L1v, LP1);
        dwt_kernel<<<dim3((((L2v + 7) / 8) + 255) / 256, NBC), blk, 0, stream>>>(ap0, ap1, d2, nullptr, L1v, LP1, L2v, LP2);
        dwt_kernel<<<dim3((((L3v + 7) / 8) + 255) / 256, NBC), blk, 0, stream>>>(ap1, ap0, d3, nullptr, L2v, LP2, L3v, LP3);
        dwt_kernel<<<dim3((((L4v + 7) / 8) + 255) / 256, NBC), blk, 0, stream>>>(ap0, ap1, d4, nullptr, L3v, LP3, L4v, LP4);

        mix_kernel<64, 64, 8, 0, 0><<<dim3((L4v + 255) / 256, B_N), blk, 0, stream>>>(ap1, ap1, ca_w, ca_b, L4v, LP4);
        mix_kernel<64, 64, 8, 0, 0><<<dim3((L4v + 255) / 256, B_N), blk, 0, stream>>>(d4, d4, cd_w + 0 * 4096, cd_b + 0 * 64, L4v, LP4);
        mix_kernel<64, 64, 8, 0, 0><<<dim3((L3v + 255) / 256, B_N), blk, 0, stream>>>(d3, d3, cd_w + 1 * 4096, cd_b + 1 * 64, L3v, LP3);
        mix_kernel<64, 64, 8, 0, 0><<<dim3((L2v + 255) / 256, B_N), blk, 0, stream>>>(d2, d2, cd_w + 2 * 4096, cd_b + 2 * 64, L2v, LP2);
        mix_kernel<64, 64, 8, 0, 0><<<dim3((L1v + 255) / 256, B_N), blk, 0, stream>>>(d1, d1, cd_w + 3 * 4096, cd_b + 3 * 64, L1v, LP1);

        idwt_kernel<<<dim3(((1038 / 8 + 1) + 255) / 256, NBC), blk, 0, stream>>>(ap1, d4, ap0, L4v, LP4, LP4, 1038, LP3);
        idwt_kernel<<<dim3(((2060 / 8 + 1) + 255) / 256, NBC), blk, 0, stream>>>(ap0, d3, ap1, L3v, LP3, LP3, 2060, LP2);
        idwt_kernel<<<dim3(((4104 / 8) + 255) / 256, NBC), blk, 0, stream>>>(ap1, d2, ap0, L2v, LP2, LP2, 4104, LP1);
        idwt_fuse_kernel<<<dim3((S_LEN / 8) / 256, NBC), blk, 0, stream>>>(ap0, d1, A, Cc, L1v, LP1, LP1);

        stats_kernel<<<NBC, blk, 0, stream>>>(A, statsBuf);
        mlp_kernel<<<dim3(S_LEN / 64, B_N), blk, 0, stream>>>(A, statsBuf, m1_w, m1_b, m2_w, m2_b);
    }

    mix_kernel<64, 32, 4, 1, 0><<<dim3(S_LEN / 256, B_N), blk, 0, stream>>>(A, Bb, p1_w, p1_b, S_LEN, S_LEN);
    mix_kernel<32, 64, 8, 0, 0><<<dim3(S_LEN / 256, B_N), blk, 0, stream>>>(Bb, (float*)d_out, p2_w, p2_b, S_LEN, S_LEN);
}

// Round 5
// 1194.200 us; speedup vs baseline: 3.0940x; 1.2535x over previous
//
#include <hip/hip_runtime.h>
#include <math.h>

#define S_LEN 8192
#define B_N   16
#define NBC   1024          // B*C rows
#define L1v 4103
#define L2v 2059
#define L3v 1037
#define L4v 526
#define LP1 4104
#define LP2 2060
#define LP3 1040
#define LP4 528

typedef __attribute__((ext_vector_type(8))) short bf16x8;
typedef __attribute__((ext_vector_type(4))) float f32x4;

__constant__ float c_dlo[16] = {
    -0.0033824159510061256f, -0.0005421323317911481f,  0.03169508781149298f,
     0.007607487324917605f,  -0.1432942383508097f,    -0.061273359067658524f,
     0.4813596512583722f,     0.7771857517005235f,     0.3644418948353314f,
    -0.05194583810770904f,   -0.027219029917056003f,   0.049137179673607506f,
     0.003808752013890615f,  -0.01495225833704823f,   -0.0003029205147213668f,
     0.0018899503327594609f
};
__constant__ float c_dhi[16] = {
    -0.0018899503327594609f, -0.0003029205147213668f,  0.01495225833704823f,
     0.003808752013890615f,  -0.049137179673607506f,  -0.027219029917056003f,
     0.05194583810770904f,    0.3644418948353314f,    -0.7771857517005235f,
     0.4813596512583722f,     0.061273359067658524f,  -0.1432942383508097f,
    -0.007607487324917605f,   0.03169508781149298f,    0.0005421323317911481f,
    -0.0033824159510061256f
};

__device__ __forceinline__ float gelu1(float x) {
    return 0.5f * x * (1.0f + erff(x * 0.70710678118654752f));
}
__device__ __forceinline__ float4 gelu4(float4 v) {
    v.x = gelu1(v.x); v.y = gelu1(v.y); v.z = gelu1(v.z); v.w = gelu1(v.w);
    return v;
}
__device__ __forceinline__ void fma4(float4& a, float w, const float4& x) {
    a.x = fmaf(w, x.x, a.x); a.y = fmaf(w, x.y, a.y);
    a.z = fmaf(w, x.z, a.z); a.w = fmaf(w, x.w, a.w);
}
__device__ __forceinline__ float4 load4g(const float* __restrict__ row, int l, int L) {
    float4 v;
    if (l >= 0 && l + 3 < L) {
        v = *(const float4*)(row + l);
    } else {
        v.x = (l     >= 0 && l     < L) ? row[l]     : 0.f;
        v.y = (l + 1 >= 0 && l + 1 < L) ? row[l + 1] : 0.f;
        v.z = (l + 2 >= 0 && l + 2 < L) ? row[l + 2] : 0.f;
        v.w = (l + 3 >= 0 && l + 3 < L) ? row[l + 3] : 0.f;
    }
    return v;
}
__device__ __forceinline__ void store4g(float* __restrict__ row, int l, int L, float4 v) {
    if (l + 3 < L) {
        *(float4*)(row + l) = v;
    } else {
        if (l     < L) row[l]     = v.x;
        if (l + 1 < L) row[l + 1] = v.y;
        if (l + 2 < L) row[l + 2] = v.z;
        if (l + 3 < L) row[l + 3] = v.w;
    }
}
__device__ __forceinline__ ushort f2bf(float f) {
    uint u = __float_as_uint(f);
    u += 0x7fffu + ((u >> 16) & 1u);
    return (ushort)(u >> 16);
}
__device__ __forceinline__ uint pack2bf(float a, float b) {
    return (uint)f2bf(a) | ((uint)f2bf(b) << 16);
}

// ---------------- lift ----------------
__global__ __launch_bounds__(256) void lift_kernel(const float* __restrict__ x,
                                                   const float* __restrict__ w,
                                                   const float* __restrict__ bias,
                                                   float* __restrict__ out) {
    int idx = blockIdx.x * 256 + threadIdx.x;
    int s = idx & (S_LEN - 1);
    int r = idx >> 13;
    int o = r & 63;
    int b = r >> 6;
    float g = -1.0f + 2.0f * (float)s / (float)(S_LEN - 1);
    out[idx] = fmaf(w[o * 2 + 0], x[b * S_LEN + s], fmaf(w[o * 2 + 1], g, bias[o]));
}

// ---------------- row stats: mean + rsqrt(var+eps) ----------------
__global__ __launch_bounds__(256) void stats_kernel(const float* __restrict__ in,
                                                    float2* __restrict__ stats) {
    const int base = blockIdx.x * S_LEN;
    const int tid = threadIdx.x;
    float s = 0.f, ss = 0.f;
#pragma unroll
    for (int i = 0; i < 8; ++i) {
        float4 v = *(const float4*)(in + base + (tid + i * 256) * 4);
        s += v.x + v.y + v.z + v.w;
        ss = fmaf(v.x, v.x, fmaf(v.y, v.y, fmaf(v.z, v.z, fmaf(v.w, v.w, ss))));
    }
    for (int off = 32; off > 0; off >>= 1) {
        s  += __shfl_down(s, off, 64);
        ss += __shfl_down(ss, off, 64);
    }
    __shared__ float sh[8];
    int lane = tid & 63, wv = tid >> 6;
    if (lane == 0) { sh[wv] = s; sh[4 + wv] = ss; }
    __syncthreads();
    if (tid == 0) {
        float tot  = sh[0] + sh[1] + sh[2] + sh[3];
        float tot2 = sh[4] + sh[5] + sh[6] + sh[7];
        float mean = tot * (1.0f / S_LEN);
        float var  = tot2 * (1.0f / S_LEN) - mean * mean;
        stats[blockIdx.x] = make_float2(mean, rsqrtf(var + 1e-5f));
    }
}

// ---------------- conv1d k=3 via bf16 MFMA; input normalized on the fly -------------
// k-order = tap*64 + c so each 32-chunk has constant tap. x staged transposed [pos][ch].
#define CWP 200   // sW pitch (ushorts) for k=192
#define CXP 72    // sXt pitch (ushorts) for 64 ch

__global__ __launch_bounds__(256) void conv3_mfma_kernel(const float* __restrict__ in,
                                                         float* __restrict__ out,
                                                         const float* __restrict__ W,   // (64,64,3)
                                                         const float* __restrict__ bias,
                                                         const float2* __restrict__ stats) {
    __shared__ ushort sW[64 * CWP];     // [o][k]  25.6 KB
    __shared__ ushort sXt[144 * CXP];   // [p][ch] 20.7 KB ; p = global (n0-8+p)
    const int b = blockIdx.y;
    const int n0 = blockIdx.x * 128;
    const int tid = threadIdx.x;

    {   // stage W reordered: sW[o][tap*64+c] = W[o][c][tap]
        const int o = tid >> 2, q = tid & 3;
        const float* wsrc = W + o * 192;
        uint* dst = (uint*)(sW + o * CWP + q * 48);
#pragma unroll
        for (int i = 0; i < 12; ++i) {
            int k = q * 48 + i * 4;
            int tap = k >> 6, c = k & 63;
            float v0 = wsrc[c * 3 + tap];
            float v1 = wsrc[(c + 1) * 3 + tap];
            float v2 = wsrc[(c + 2) * 3 + tap];
            float v3 = wsrc[(c + 3) * 3 + tap];
            dst[2 * i]     = pack2bf(v0, v1);
            dst[2 * i + 1] = pack2bf(v2, v3);
        }
    }
    {   // stage x^T normalized (zero outside [0,S_LEN))
        const int ch = tid >> 2, q = tid & 3;
        const int rowi = b * 64 + ch;
        const float2 st = stats[rowi];
        const float* row = in + (size_t)rowi * S_LEN;
#pragma unroll
        for (int i = 0; i < 9; ++i) {
            int p = q * 36 + i * 4;
            int l = n0 - 8 + p;
            float4 v;
            if (l >= 0 && l + 3 < S_LEN) {
                v = *(const float4*)(row + l);
                v.x = (v.x - st.x) * st.y; v.y = (v.y - st.x) * st.y;
                v.z = (v.z - st.x) * st.y; v.w = (v.w - st.x) * st.y;
            } else {
                v.x = (l     >= 0 && l     < S_LEN) ? (row[l]     - st.x) * st.y : 0.f;
                v.y = (l + 1 >= 0 && l + 1 < S_LEN) ? (row[l + 1] - st.x) * st.y : 0.f;
                v.z = (l + 2 >= 0 && l + 2 < S_LEN) ? (row[l + 2] - st.x) * st.y : 0.f;
                v.w = (l + 3 >= 0 && l + 3 < S_LEN) ? (row[l + 3] - st.x) * st.y : 0.f;
            }
            sXt[(p + 0) * CXP + ch] = f2bf(v.x);
            sXt[(p + 1) * CXP + ch] = f2bf(v.y);
            sXt[(p + 2) * CXP + ch] = f2bf(v.z);
            sXt[(p + 3) * CXP + ch] = f2bf(v.w);
        }
    }
    __syncthreads();

    const int w = tid >> 6, l = tid & 63, g = l >> 4, c = l & 15;
    f32x4 acc[2][4];
#pragma unroll
    for (int mt = 0; mt < 4; ++mt) {
        float4 bv = *(const float4*)(bias + 16 * mt + 4 * g);
#pragma unroll
        for (int t = 0; t < 2; ++t) {
            acc[t][mt][0] = bv.x; acc[t][mt][1] = bv.y;
            acc[t][mt][2] = bv.z; acc[t][mt][3] = bv.w;
        }
    }
#pragma unroll
    for (int kk = 0; kk < 6; ++kk) {
        const int tap = kk >> 1;
        bf16x8 af[4];
#pragma unroll
        for (int mt = 0; mt < 4; ++mt)
            af[mt] = *(bf16x8*)(sW + (16 * mt + c) * CWP + kk * 32 + 8 * g);
#pragma unroll
        for (int t = 0; t < 2; ++t) {
            const int nl = 32 * w + 16 * t + c;
            const int p = nl + tap + 7;
            bf16x8 xb = *(bf16x8*)(sXt + p * CXP + (kk & 1) * 32 + 8 * g);
#pragma unroll
            for (int mt = 0; mt < 4; ++mt)
                acc[t][mt] = __builtin_amdgcn_mfma_f32_16x16x32_bf16(af[mt], xb, acc[t][mt], 0, 0, 0);
        }
    }
#pragma unroll
    for (int t = 0; t < 2; ++t) {
        const int nl = 32 * w + 16 * t + c;
#pragma unroll
        for (int mt = 0; mt < 4; ++mt)
#pragma unroll
            for (int r = 0; r < 4; ++r) {
                int m = 16 * mt + 4 * g + r;
                out[((size_t)(b * 64 + m)) * S_LEN + n0 + nl] = acc[t][mt][r];
            }
    }
}

// ---------------- channel mix GEMM (f32, wavelet-domain + head) ----------------
template <int CIN, int COUT, int TO, int ACT, int RES>
__global__ __launch_bounds__(256) void mix_kernel(const float* __restrict__ in,
                                                  float* __restrict__ out,
                                                  const float* __restrict__ W,
                                                  const float* __restrict__ bias,
                                                  int L, int LP) {
    constexpr int NOG = COUT / TO;
    constexpr int NLG = 256 / NOG;
    constexpr int LT  = NLG * 8;
    constexpr int KC  = (CIN < 32) ? CIN : 32;
    constexpr int NCH = CIN / KC;
    __shared__ float sx[KC * LT];
    __shared__ float sw[KC * COUT];
    const int b = blockIdx.y;
    const int l0 = blockIdx.x * LT;
    const int tid = threadIdx.x;
    const int og = tid / NLG;
    const int lg = tid % NLG;
    const int la = l0 + lg * 4;
    const int lb = la + NLG * 4;

    float4 acc_a[TO], acc_b[TO];
#pragma unroll
    for (int j = 0; j < TO; ++j) {
        float bv = bias[og * TO + j];
        acc_a[j] = make_float4(bv, bv, bv, bv);
        acc_b[j] = acc_a[j];
    }

    for (int ch = 0; ch < NCH; ++ch) {
        const int c0 = ch * KC;
        if (ch) __syncthreads();
        for (int e = tid; e < KC * LT / 4; e += 256) {
            const int cc = e / (LT / 4);
            const int p  = e % (LT / 4);
            const int l  = l0 + p * 4;
            const float* row = in + ((size_t)(b * CIN + c0 + cc)) * LP;
            *(float4*)(sx + cc * LT + p * 4) = load4g(row, l, L);
        }
        for (int e = tid; e < KC * COUT; e += 256) {
            const int cc = e / COUT;
            const int o  = e % COUT;
            sw[cc * COUT + o] = W[o * CIN + c0 + cc];
        }
        __syncthreads();
#pragma unroll 4
        for (int cc = 0; cc < KC; ++cc) {
            const float4 xa = *(const float4*)(sx + cc * LT + lg * 4);
            const float4 xb = *(const float4*)(sx + cc * LT + NLG * 4 + lg * 4);
            const float* swp = sw + cc * COUT + og * TO;
            const float4 w0 = *(const float4*)(swp);
            fma4(acc_a[0], w0.x, xa); fma4(acc_b[0], w0.x, xb);
            fma4(acc_a[1], w0.y, xa); fma4(acc_b[1], w0.y, xb);
            fma4(acc_a[2], w0.z, xa); fma4(acc_b[2], w0.z, xb);
            fma4(acc_a[3], w0.w, xa); fma4(acc_b[3], w0.w, xb);
            if constexpr (TO == 8) {
                const float4 w1 = *(const float4*)(swp + 4);
                fma4(acc_a[4], w1.x, xa); fma4(acc_b[4], w1.x, xb);
                fma4(acc_a[5], w1.y, xa); fma4(acc_b[5], w1.y, xb);
                fma4(acc_a[6], w1.z, xa); fma4(acc_b[6], w1.z, xb);
                fma4(acc_a[7], w1.w, xa); fma4(acc_b[7], w1.w, xb);
            }
        }
    }
#pragma unroll
    for (int j = 0; j < TO; ++j) {
        float* row = out + ((size_t)(b * COUT + og * TO + j)) * LP;
        float4 va = acc_a[j], vb = acc_b[j];
        if (ACT) { va = gelu4(va); vb = gelu4(vb); }
        if (RES) {
            float4 ra = load4g(row, la, L), rb = load4g(row, lb, L);
            va.x += ra.x; va.y += ra.y; va.z += ra.z; va.w += ra.w;
            vb.x += rb.x; vb.y += rb.y; vb.z += rb.z; vb.w += rb.w;
        }
        store4g(row, la, L, va);
        store4g(row, lb, L, vb);
    }
}

// ---------------- fused MLP: A += W2 * gelu(W1 * inorm(A) + b1) + b2 (bf16 MFMA) ----------
#define W1P 72
#define W2P 136
#define XP  66
#define MP  136

__global__ __launch_bounds__(256) void mlp_kernel(float* __restrict__ A,
                                                  const float2* __restrict__ stats,
                                                  const float* __restrict__ W1,
                                                  const float* __restrict__ b1,
                                                  const float* __restrict__ W2,
                                                  const float* __restrict__ b2) {
    __shared__ ushort sW1[128 * W1P];
    __shared__ ushort sW2[64 * W2P];
    __shared__ ushort sX [64 * XP];
    __shared__ ushort sMid[64 * MP];
    const int b  = blockIdx.y;
    const int n0 = blockIdx.x * 64;
    const int tid = threadIdx.x;

    {   // stage W1 (128x64) -> bf16 [m][k]
        int row = tid >> 1, half = tid & 1;
        const float* src = W1 + row * 64 + half * 32;
        uint* dst = (uint*)(sW1 + row * W1P + half * 32);
#pragma unroll
        for (int i = 0; i < 8; ++i) {
            float4 v = *(const float4*)(src + 4 * i);
            dst[2 * i]     = pack2bf(v.x, v.y);
            dst[2 * i + 1] = pack2bf(v.z, v.w);
        }
    }
    {   // stage W2 (64x128) -> bf16 [m][k]
        int row = tid >> 2, q = tid & 3;
        const float* src = W2 + row * 128 + q * 32;
        uint* dst = (uint*)(sW2 + row * W2P + q * 32);
#pragma unroll
        for (int i = 0; i < 8; ++i) {
            float4 v = *(const float4*)(src + 4 * i);
            dst[2 * i]     = pack2bf(v.x, v.y);
            dst[2 * i + 1] = pack2bf(v.z, v.w);
        }
    }
    {   // stage xn tile: normalize A[ch][n0..n0+63] -> bf16 [ch][pos]
        int ch = tid >> 2, part = tid & 3;
        float2 st = stats[b * 64 + ch];
        const float* src = A + ((size_t)(b * 64 + ch)) * S_LEN + n0 + part * 16;
        uint* dst = (uint*)(sX + ch * XP + part * 16);
#pragma unroll
        for (int i = 0; i < 4; ++i) {
            float4 v = *(const float4*)(src + 4 * i);
            v.x = (v.x - st.x) * st.y; v.y = (v.y - st.x) * st.y;
            v.z = (v.z - st.x) * st.y; v.w = (v.w - st.x) * st.y;
            dst[2 * i]     = pack2bf(v.x, v.y);
            dst[2 * i + 1] = pack2bf(v.z, v.w);
        }
    }
    __syncthreads();

    const int w = tid >> 6;
    const int l = tid & 63;
    const int g = l >> 4;
    const int c = l & 15;
    const int nl = 16 * w + c;

    bf16x8 xb[2];
#pragma unroll
    for (int kk = 0; kk < 2; ++kk)
#pragma unroll
        for (int j = 0; j < 8; ++j)
            xb[kk][j] = (short)sX[(kk * 32 + 8 * g + j) * XP + nl];

    f32x4 acc1[8];
#pragma unroll
    for (int mt = 0; mt < 8; ++mt) {
        float4 bv = *(const float4*)(b1 + 16 * mt + 4 * g);
        acc1[mt][0] = bv.x; acc1[mt][1] = bv.y; acc1[mt][2] = bv.z; acc1[mt][3] = bv.w;
    }
#pragma unroll
    for (int kk = 0; kk < 2; ++kk) {
#pragma unroll
        for (int mt = 0; mt < 8; ++mt) {
            bf16x8 af = *(bf16x8*)(sW1 + (16 * mt + c) * W1P + kk * 32 + 8 * g);
            acc1[mt] = __builtin_amdgcn_mfma_f32_16x16x32_bf16(af, xb[kk], acc1[mt], 0, 0, 0);
        }
    }
#pragma unroll
    for (int mt = 0; mt < 8; ++mt)
#pragma unroll
        for (int r = 0; r < 4; ++r)
            sMid[nl * MP + 16 * mt + 4 * g + r] = f2bf(gelu1(acc1[mt][r]));

    bf16x8 mb[4];
#pragma unroll
    for (int kk = 0; kk < 4; ++kk)
        mb[kk] = *(bf16x8*)(sMid + nl * MP + kk * 32 + 8 * g);

    f32x4 acc2[4];
#pragma unroll
    for (int mt = 0; mt < 4; ++mt) {
        float4 bv = *(const float4*)(b2 + 16 * mt + 4 * g);
        acc2[mt][0] = bv.x; acc2[mt][1] = bv.y; acc2[mt][2] = bv.z; acc2[mt][3] = bv.w;
    }
#pragma unroll
    for (int kk = 0; kk < 4; ++kk) {
#pragma unroll
        for (int mt = 0; mt < 4; ++mt) {
            bf16x8 af = *(bf16x8*)(sW2 + (16 * mt + c) * W2P + kk * 32 + 8 * g);
            acc2[mt] = __builtin_amdgcn_mfma_f32_16x16x32_bf16(af, mb[kk], acc2[mt], 0, 0, 0);
        }
    }
#pragma unroll
    for (int mt = 0; mt < 4; ++mt) {
#pragma unroll
        for (int r = 0; r < 4; ++r) {
            int m = 16 * mt + 4 * g + r;
            float* p = A + ((size_t)(b * 64 + m)) * S_LEN + n0 + nl;
            *p = acc2[mt][r] + *p;
        }
    }
}

// ---------------- fused 4-level DWT, one block per row ----------------
__device__ __forceinline__ void dwt_lds(const float* __restrict__ in, int Sin,
                                        float* __restrict__ aout,
                                        float* __restrict__ dout_g, int Lout, int tid) {
    for (int t = tid; t < Lout; t += 256) {
        float lo = 0.f, hi = 0.f;
#pragma unroll
        for (int k = 0; k < 16; ++k) {
            int i = 2 * t + k - 14;
            i = (i < 0) ? (-1 - i) : i;
            i = (i >= Sin) ? (2 * Sin - 1 - i) : i;
            float v = in[i];
            lo = fmaf(v, c_dlo[15 - k], lo);
            hi = fmaf(v, c_dhi[15 - k], hi);
        }
        aout[t] = lo;
        dout_g[t] = hi;
    }
}

__global__ __launch_bounds__(256) void dwt_full_kernel(const float* __restrict__ A,
                                                       const float2* __restrict__ stats,
                                                       float* __restrict__ d1,
                                                       float* __restrict__ d2,
                                                       float* __restrict__ d3,
                                                       float* __restrict__ d4,
                                                       float* __restrict__ a4) {
    __shared__ float bufA[4104];
    __shared__ float bufB[2060];
    const int row = blockIdx.x;
    const int tid = threadIdx.x;
    const float2 st = stats[row];
    const float* x = A + (size_t)row * S_LEN;
    float* d1r = d1 + (size_t)row * LP1;

    // level 1: 513 groups of 8 outputs; lo -> bufA, hi -> d1 (global)
    for (int g = tid; g < 513; g += 256) {
        const int base = 16 * g - 16;
        float xb[32];
        if (base >= 0 && base + 32 <= S_LEN) {
#pragma unroll
            for (int q = 0; q < 8; ++q) {
                float4 v = *(const float4*)(x + base + 4 * q);
                v.x = (v.x - st.x) * st.y; v.y = (v.y - st.x) * st.y;
                v.z = (v.z - st.x) * st.y; v.w = (v.w - st.x) * st.y;
                *(float4*)(xb + 4 * q) = v;
            }
        } else {
#pragma unroll
            for (int loc = 0; loc < 32; ++loc) {
                int i = base + loc;
                i = (i < 0) ? (-1 - i) : i;
                i = (i >= S_LEN) ? (2 * S_LEN - 1 - i) : i;
                xb[loc] = (x[i] - st.x) * st.y;
            }
        }
        float lo[8], hi[8];
#pragma unroll
        for (int j = 0; j < 8; ++j) {
            float l0 = 0.f, h0 = 0.f;
#pragma unroll
            for (int k = 0; k < 16; ++k) {
                float v = xb[2 * j + k + 2];
                l0 = fmaf(v, c_dlo[15 - k], l0);
                h0 = fmaf(v, c_dhi[15 - k], h0);
            }
            lo[j] = l0; hi[j] = h0;
        }
        const int t0 = 8 * g;
#pragma unroll
        for (int j = 0; j < 8; ++j)
            if (t0 + j < L1v) bufA[t0 + j] = lo[j];
        store4g(d1r, t0,     L1v, make_float4(hi[0], hi[1], hi[2], hi[3]));
        store4g(d1r, t0 + 4, L1v, make_float4(hi[4], hi[5], hi[6], hi[7]));
    }
    __syncthreads();
    dwt_lds(bufA, L1v, bufB, d2 + (size_t)row * LP2, L2v, tid);   // a1 -> a2
    __syncthreads();
    dwt_lds(bufB, L2v, bufA, d3 + (size_t)row * LP3, L3v, tid);   // a2 -> a3
    __syncthreads();
    dwt_lds(bufA, L3v, bufB, d4 + (size_t)row * LP4, L4v, tid);   // a3 -> a4
    __syncthreads();
    float* a4r = a4 + (size_t)row * LP4;
    for (int i = tid; i < L4v; i += 256) a4r[i] = bufB[i];
}

// ---------------- fused 4-level IDWT + gelu-residual + stats, one block per row ----------
__device__ __forceinline__ void idwt_lds(const float* __restrict__ a,
                                         const float* __restrict__ d,
                                         int Lout, float* __restrict__ out, int tid) {
    for (int t = tid; t < Lout; t += 256) {
        int m0 = t >> 1;
        float acc = 0.f;
        if ((t & 1) == 0) {
#pragma unroll
            for (int j = 0; j < 8; ++j)
                acc += a[m0 + j] * c_dlo[2 * j + 1] + d[m0 + j] * c_dlo[14 - 2 * j];
        } else {
#pragma unroll
            for (int j = 0; j < 8; ++j)
                acc += a[m0 + j] * c_dlo[2 * j] - d[m0 + j] * c_dlo[15 - 2 * j];
        }
        out[t] = acc;
    }
}

__global__ __launch_bounds__(256) void idwt_full_kernel(const float* __restrict__ a4,
                                                        const float* __restrict__ d4,
                                                        const float* __restrict__ d3,
                                                        const float* __restrict__ d2,
                                                        const float* __restrict__ d1,
                                                        float* __restrict__ h,
                                                        const float* __restrict__ xs,
                                                        float2* __restrict__ statsOut) {
    __shared__ float bufY[4104];
    __shared__ float bufA[4104];
    __shared__ float bufD[4104];
    const int row = blockIdx.x;
    const int tid = threadIdx.x;

    for (int i = tid; i < L4v; i += 256) {
        bufA[i] = a4[(size_t)row * LP4 + i];
        bufD[i] = d4[(size_t)row * LP4 + i];
    }
    __syncthreads();
    idwt_lds(bufA, bufD, 1038, bufY, tid);          // level 4 -> 1038
    __syncthreads();
    for (int i = tid; i < L3v; i += 256) bufD[i] = d3[(size_t)row * LP3 + i];
    __syncthreads();
    idwt_lds(bufY, bufD, 2060, bufA, tid);          // level 3 -> 2060
    __syncthreads();
    for (int i = tid; i < L2v; i += 256) bufD[i] = d2[(size_t)row * LP2 + i];
    __syncthreads();
    idwt_lds(bufA, bufD, 4104, bufY, tid);          // level 2 -> 4104
    __syncthreads();
    for (int i = tid; i < L1v; i += 256) bufD[i] = d1[(size_t)row * LP1 + i];
    __syncthreads();

    // level 1 (8192) fused: h += gelu(y + xs); also accumulate stats of updated h
    float* hrow = h + (size_t)row * S_LEN;
    const float* srow = xs + (size_t)row * S_LEN;
    float s = 0.f, ss = 0.f;
#pragma unroll
    for (int it = 0; it < 8; ++it) {
        const int t0 = (it * 256 + tid) * 4;
        const int m0 = t0 >> 1;
        float y[4];
#pragma unroll
        for (int e = 0; e < 2; ++e) {
            float ye = 0.f, yo = 0.f;
#pragma unroll
            for (int j = 0; j < 8; ++j) {
                float av = bufY[m0 + e + j];
                float dv = bufD[m0 + e + j];
                ye = fmaf(av, c_dlo[2 * j + 1], ye);
                ye = fmaf(dv, c_dlo[14 - 2 * j], ye);
                yo = fmaf(av, c_dlo[2 * j], yo);
                yo = fmaf(dv, -c_dlo[15 - 2 * j], yo);
            }
            y[2 * e] = ye; y[2 * e + 1] = yo;
        }
        float4 sv = *(const float4*)(srow + t0);
        float4 hv = *(const float4*)(hrow + t0);
        hv.x += gelu1(y[0] + sv.x);
        hv.y += gelu1(y[1] + sv.y);
        hv.z += gelu1(y[2] + sv.z);
        hv.w += gelu1(y[3] + sv.w);
        *(float4*)(hrow + t0) = hv;
        s += hv.x + hv.y + hv.z + hv.w;
        ss = fmaf(hv.x, hv.x, fmaf(hv.y, hv.y, fmaf(hv.z, hv.z, fmaf(hv.w, hv.w, ss))));
    }
    // row reduction for next inorm (pre-MLP)
    for (int off = 32; off > 0; off >>= 1) {
        s  += __shfl_down(s, off, 64);
        ss += __shfl_down(ss, off, 64);
    }
    __syncthreads();
    int lane = tid & 63, wv = tid >> 6;
    if (lane == 0) { bufA[wv] = s; bufA[4 + wv] = ss; }
    __syncthreads();
    if (tid == 0) {
        float tot  = bufA[0] + bufA[1] + bufA[2] + bufA[3];
        float tot2 = bufA[4] + bufA[5] + bufA[6] + bufA[7];
        float mean = tot * (1.0f / S_LEN);
        float var  = tot2 * (1.0f / S_LEN) - mean * mean;
        statsOut[row] = make_float2(mean, rsqrtf(var + 1e-5f));
    }
}

extern "C" void kernel_launch(void* const* d_in, const int* in_sizes, int n_in,
                              void* d_out, int out_size, void* d_ws, size_t ws_size,
                              hipStream_t stream) {
    const float* x       = (const float*)d_in[0];
    const float* lift_w  = (const float*)d_in[1];
    const float* lift_b  = (const float*)d_in[2];
    const float* blk_w_w = (const float*)d_in[3];
    const float* blk_w_b = (const float*)d_in[4];
    const float* blk_ca_w= (const float*)d_in[5];
    const float* blk_ca_b= (const float*)d_in[6];
    const float* blk_cd_w= (const float*)d_in[7];
    const float* blk_cd_b= (const float*)d_in[8];
    const float* blk_m1_w= (const float*)d_in[9];
    const float* blk_m1_b= (const float*)d_in[10];
    const float* blk_m2_w= (const float*)d_in[11];
    const float* blk_m2_b= (const float*)d_in[12];
    const float* p1_w    = (const float*)d_in[13];
    const float* p1_b    = (const float*)d_in[14];
    const float* p2_w    = (const float*)d_in[15];
    const float* p2_b    = (const float*)d_in[16];

    float* ws = (float*)d_ws;
    const size_t T32 = (size_t)NBC * S_LEN;
    float* A  = ws;                                  // h / xo (residual stream)
    float* Bb = ws + T32;                            // head p1 output
    float* Cc = ws + 2 * T32;                        // xs (conv out)
    float* d1 = ws + 4 * T32;
    float* d2 = d1 + (size_t)NBC * LP1;
    float* d3 = d2 + (size_t)NBC * LP2;
    float* d4 = d3 + (size_t)NBC * LP3;
    float* ap0 = d4 + (size_t)NBC * LP4;
    float* ap1 = ap0 + (size_t)NBC * 4104;
    float2* statsBuf = (float2*)(ap1 + (size_t)NBC * 4104);

    dim3 blk(256);

    lift_kernel<<<(NBC * S_LEN) / 256, blk, 0, stream>>>(x, lift_w, lift_b, A);

    for (int i = 0; i < 4; ++i) {
        const float* w_w  = blk_w_w  + (size_t)i * 64 * 64 * 3;
        const float* w_b  = blk_w_b  + (size_t)i * 64;
        const float* ca_w = blk_ca_w + (size_t)i * 64 * 64;
        const float* ca_b = blk_ca_b + (size_t)i * 64;
        const float* cd_w = blk_cd_w + (size_t)i * 4 * 64 * 64;
        const float* cd_b = blk_cd_b + (size_t)i * 4 * 64;
        const float* m1_w = blk_m1_w + (size_t)i * 128 * 64;
        const float* m1_b = blk_m1_b + (size_t)i * 128;
        const float* m2_w = blk_m2_w + (size_t)i * 64 * 128;
        const float* m2_b = blk_m2_b + (size_t)i * 64;

        stats_kernel<<<NBC, blk, 0, stream>>>(A, statsBuf);
        conv3_mfma_kernel<<<dim3(S_LEN / 128, B_N), blk, 0, stream>>>(A, Cc, w_w, w_b, statsBuf);
        dwt_full_kernel<<<NBC, blk, 0, stream>>>(A, statsBuf, d1, d2, d3, d4, ap1);

        mix_kernel<64, 64, 8, 0, 0><<<dim3((L4v + 255) / 256, B_N), blk, 0, stream>>>(ap1, ap1, ca_w, ca_b, L4v, LP4);
        mix_kernel<64, 64, 8, 0, 0><<<dim3((L4v + 255) / 256, B_N), blk, 0, stream>>>(d4, d4, cd_w + 0 * 4096, cd_b + 0 * 64, L4v, LP4);
        mix_kernel<64, 64, 8, 0, 0><<<dim3((L3v + 255) / 256, B_N), blk, 0, stream>>>(d3, d3, cd_w + 1 * 4096, cd_b + 1 * 64, L3v, LP3);
        mix_kernel<64, 64, 8, 0, 0><<<dim3((L2v + 255) / 256, B_N), blk, 0, stream>>>(d2, d2, cd_w + 2 * 4096, cd_b + 2 * 64, L2v, LP2);
        mix_kernel<64, 64, 8, 0, 0><<<dim3((L1v + 255) / 256, B_N), blk, 0, stream>>>(d1, d1, cd_w + 3 * 4096, cd_b + 3 * 64, L1v, LP1);

        idwt_full_kernel<<<NBC, blk, 0, stream>>>(ap1, d4, d3, d2, d1, A, Cc, statsBuf);
        mlp_kernel<<<dim3(S_LEN / 64, B_N), blk, 0, stream>>>(A, statsBuf, m1_w, m1_b, m2_w, m2_b);
    }

    mix_kernel<64, 32, 4, 1, 0><<<dim3(S_LEN / 256, B_N), blk, 0, stream>>>(A, Bb, p1_w, p1_b, S_LEN, S_LEN);
    mix_kernel<32, 64, 8, 0, 0><<<dim3(S_LEN / 256, B_N), blk, 0, stream>>>(Bb, (float*)d_out, p2_w, p2_b, S_LEN, S_LEN);
}

// Round 6
// 828.697 us; speedup vs baseline: 4.4586x; 1.4411x over previous
//
#include <hip/hip_runtime.h>
#include <math.h>

#define S_LEN 8192
#define B_N   16
#define NBC   1024          // B*C rows
#define L1v 4103
#define L2v 2059
#define L3v 1037
#define L4v 526
#define LP1 4104
#define LP2 2060
#define LP3 1040
#define LP4 528

typedef __attribute__((ext_vector_type(8))) short bf16x8;
typedef __attribute__((ext_vector_type(4))) float f32x4;

__constant__ float c_dlo[16] = {
    -0.0033824159510061256f, -0.0005421323317911481f,  0.03169508781149298f,
     0.007607487324917605f,  -0.1432942383508097f,    -0.061273359067658524f,
     0.4813596512583722f,     0.7771857517005235f,     0.3644418948353314f,
    -0.05194583810770904f,   -0.027219029917056003f,   0.049137179673607506f,
     0.003808752013890615f,  -0.01495225833704823f,   -0.0003029205147213668f,
     0.0018899503327594609f
};
__constant__ float c_dhi[16] = {
    -0.0018899503327594609f, -0.0003029205147213668f,  0.01495225833704823f,
     0.003808752013890615f,  -0.049137179673607506f,  -0.027219029917056003f,
     0.05194583810770904f,    0.3644418948353314f,    -0.7771857517005235f,
     0.4813596512583722f,     0.061273359067658524f,  -0.1432942383508097f,
    -0.007607487324917605f,   0.03169508781149298f,    0.0005421323317911481f,
    -0.0033824159510061256f
};

__device__ __forceinline__ float gelu1(float x) {
    return 0.5f * x * (1.0f + erff(x * 0.70710678118654752f));
}
__device__ __forceinline__ float4 load4g(const float* __restrict__ row, int l, int L) {
    float4 v;
    if (l >= 0 && l + 3 < L) {
        v = *(const float4*)(row + l);
    } else {
        v.x = (l     >= 0 && l     < L) ? row[l]     : 0.f;
        v.y = (l + 1 >= 0 && l + 1 < L) ? row[l + 1] : 0.f;
        v.z = (l + 2 >= 0 && l + 2 < L) ? row[l + 2] : 0.f;
        v.w = (l + 3 >= 0 && l + 3 < L) ? row[l + 3] : 0.f;
    }
    return v;
}
__device__ __forceinline__ void store4g(float* __restrict__ row, int l, int L, float4 v) {
    if (l + 3 < L) {
        *(float4*)(row + l) = v;
    } else {
        if (l     < L) row[l]     = v.x;
        if (l + 1 < L) row[l + 1] = v.y;
        if (l + 2 < L) row[l + 2] = v.z;
        if (l + 3 < L) row[l + 3] = v.w;
    }
}
__device__ __forceinline__ ushort f2bf(float f) {
    uint u = __float_as_uint(f);
    u += 0x7fffu + ((u >> 16) & 1u);
    return (ushort)(u >> 16);
}
__device__ __forceinline__ uint pack2bf(float a, float b) {
    return (uint)f2bf(a) | ((uint)f2bf(b) << 16);
}

// ---------------- lift ----------------
__global__ __launch_bounds__(256) void lift_kernel(const float* __restrict__ x,
                                                   const float* __restrict__ w,
                                                   const float* __restrict__ bias,
                                                   float* __restrict__ out) {
    int idx = blockIdx.x * 256 + threadIdx.x;
    int s = idx & (S_LEN - 1);
    int r = idx >> 13;
    int o = r & 63;
    int b = r >> 6;
    float g = -1.0f + 2.0f * (float)s / (float)(S_LEN - 1);
    out[idx] = fmaf(w[o * 2 + 0], x[b * S_LEN + s], fmaf(w[o * 2 + 1], g, bias[o]));
}

// ---------------- row stats: mean + rsqrt(var+eps) ----------------
__global__ __launch_bounds__(256) void stats_kernel(const float* __restrict__ in,
                                                    float2* __restrict__ stats) {
    const int base = blockIdx.x * S_LEN;
    const int tid = threadIdx.x;
    float s = 0.f, ss = 0.f;
#pragma unroll
    for (int i = 0; i < 8; ++i) {
        float4 v = *(const float4*)(in + base + (tid + i * 256) * 4);
        s += v.x + v.y + v.z + v.w;
        ss = fmaf(v.x, v.x, fmaf(v.y, v.y, fmaf(v.z, v.z, fmaf(v.w, v.w, ss))));
    }
    for (int off = 32; off > 0; off >>= 1) {
        s  += __shfl_down(s, off, 64);
        ss += __shfl_down(ss, off, 64);
    }
    __shared__ float sh[8];
    int lane = tid & 63, wv = tid >> 6;
    if (lane == 0) { sh[wv] = s; sh[4 + wv] = ss; }
    __syncthreads();
    if (tid == 0) {
        float tot  = sh[0] + sh[1] + sh[2] + sh[3];
        float tot2 = sh[4] + sh[5] + sh[6] + sh[7];
        float mean = tot * (1.0f / S_LEN);
        float var  = tot2 * (1.0f / S_LEN) - mean * mean;
        stats[blockIdx.x] = make_float2(mean, rsqrtf(var + 1e-5f));
    }
}

// ---------------- conv1d k=3 via bf16 MFMA; input normalized on the fly -------------
#define CWP 200   // sW pitch (ushorts) for k=192
#define CXP 72    // sXt pitch (ushorts) for 64 ch

__global__ __launch_bounds__(256) void conv3_mfma_kernel(const float* __restrict__ in,
                                                         float* __restrict__ out,
                                                         const float* __restrict__ W,   // (64,64,3)
                                                         const float* __restrict__ bias,
                                                         const float2* __restrict__ stats) {
    __shared__ ushort sW[64 * CWP];
    __shared__ ushort sXt[144 * CXP];
    const int b = blockIdx.y;
    const int n0 = blockIdx.x * 128;
    const int tid = threadIdx.x;

    {   // stage W reordered: sW[o][tap*64+c] = W[o][c][tap]
        const int o = tid >> 2, q = tid & 3;
        const float* wsrc = W + o * 192;
        uint* dst = (uint*)(sW + o * CWP + q * 48);
#pragma unroll
        for (int i = 0; i < 12; ++i) {
            int k = q * 48 + i * 4;
            int tap = k >> 6, c = k & 63;
            float v0 = wsrc[c * 3 + tap];
            float v1 = wsrc[(c + 1) * 3 + tap];
            float v2 = wsrc[(c + 2) * 3 + tap];
            float v3 = wsrc[(c + 3) * 3 + tap];
            dst[2 * i]     = pack2bf(v0, v1);
            dst[2 * i + 1] = pack2bf(v2, v3);
        }
    }
    {   // stage x^T normalized (zero outside [0,S_LEN))
        const int ch = tid >> 2, q = tid & 3;
        const int rowi = b * 64 + ch;
        const float2 st = stats[rowi];
        const float* row = in + (size_t)rowi * S_LEN;
#pragma unroll
        for (int i = 0; i < 9; ++i) {
            int p = q * 36 + i * 4;
            int l = n0 - 8 + p;
            float4 v;
            if (l >= 0 && l + 3 < S_LEN) {
                v = *(const float4*)(row + l);
                v.x = (v.x - st.x) * st.y; v.y = (v.y - st.x) * st.y;
                v.z = (v.z - st.x) * st.y; v.w = (v.w - st.x) * st.y;
            } else {
                v.x = (l     >= 0 && l     < S_LEN) ? (row[l]     - st.x) * st.y : 0.f;
                v.y = (l + 1 >= 0 && l + 1 < S_LEN) ? (row[l + 1] - st.x) * st.y : 0.f;
                v.z = (l + 2 >= 0 && l + 2 < S_LEN) ? (row[l + 2] - st.x) * st.y : 0.f;
                v.w = (l + 3 >= 0 && l + 3 < S_LEN) ? (row[l + 3] - st.x) * st.y : 0.f;
            }
            sXt[(p + 0) * CXP + ch] = f2bf(v.x);
            sXt[(p + 1) * CXP + ch] = f2bf(v.y);
            sXt[(p + 2) * CXP + ch] = f2bf(v.z);
            sXt[(p + 3) * CXP + ch] = f2bf(v.w);
        }
    }
    __syncthreads();

    const int w = tid >> 6, l = tid & 63, g = l >> 4, c = l & 15;
    f32x4 acc[2][4];
#pragma unroll
    for (int mt = 0; mt < 4; ++mt) {
        float4 bv = *(const float4*)(bias + 16 * mt + 4 * g);
#pragma unroll
        for (int t = 0; t < 2; ++t) {
            acc[t][mt][0] = bv.x; acc[t][mt][1] = bv.y;
            acc[t][mt][2] = bv.z; acc[t][mt][3] = bv.w;
        }
    }
#pragma unroll
    for (int kk = 0; kk < 6; ++kk) {
        const int tap = kk >> 1;
        bf16x8 af[4];
#pragma unroll
        for (int mt = 0; mt < 4; ++mt)
            af[mt] = *(bf16x8*)(sW + (16 * mt + c) * CWP + kk * 32 + 8 * g);
#pragma unroll
        for (int t = 0; t < 2; ++t) {
            const int nl = 32 * w + 16 * t + c;
            const int p = nl + tap + 7;
            bf16x8 xb = *(bf16x8*)(sXt + p * CXP + (kk & 1) * 32 + 8 * g);
#pragma unroll
            for (int mt = 0; mt < 4; ++mt)
                acc[t][mt] = __builtin_amdgcn_mfma_f32_16x16x32_bf16(af[mt], xb, acc[t][mt], 0, 0, 0);
        }
    }
#pragma unroll
    for (int t = 0; t < 2; ++t) {
        const int nl = 32 * w + 16 * t + c;
#pragma unroll
        for (int mt = 0; mt < 4; ++mt)
#pragma unroll
            for (int r = 0; r < 4; ++r) {
                int m = 16 * mt + 4 * g + r;
                out[((size_t)(b * 64 + m)) * S_LEN + n0 + nl] = acc[t][mt][r];
            }
    }
}

// ---------------- consolidated wavelet-domain channel mix (bf16 MFMA, in-place) --------
#define WMP 72
#define WXP 136

__global__ __launch_bounds__(256) void wmix_kernel(float* __restrict__ d1,
                                                   float* __restrict__ d2,
                                                   float* __restrict__ d3,
                                                   float* __restrict__ d4,
                                                   float* __restrict__ a4,
                                                   const float* __restrict__ cd_w,
                                                   const float* __restrict__ cd_b,
                                                   const float* __restrict__ ca_w,
                                                   const float* __restrict__ ca_b) {
    __shared__ ushort sW[64 * WMP];
    __shared__ ushort sX[64 * WXP];
    const int b = blockIdx.y;
    const int t = blockIdx.x;
    float* buf; const float* W; const float* bias; int L, LP, l0;
    if (t < 33)      { buf = d1; W = cd_w + 3 * 4096; bias = cd_b + 3 * 64; L = L1v; LP = LP1; l0 = t * 128; }
    else if (t < 50) { buf = d2; W = cd_w + 2 * 4096; bias = cd_b + 2 * 64; L = L2v; LP = LP2; l0 = (t - 33) * 128; }
    else if (t < 59) { buf = d3; W = cd_w + 1 * 4096; bias = cd_b + 1 * 64; L = L3v; LP = LP3; l0 = (t - 50) * 128; }
    else if (t < 64) { buf = d4; W = cd_w;            bias = cd_b;          L = L4v; LP = LP4; l0 = (t - 59) * 128; }
    else             { buf = a4; W = ca_w;            bias = ca_b;          L = L4v; LP = LP4; l0 = (t - 64) * 128; }
    const int tid = threadIdx.x;
    {   // stage W (64x64) -> bf16 [o][c]
        int row = tid >> 2, q = tid & 3;
        const float* src = W + row * 64 + q * 16;
        uint* dst = (uint*)(sW + row * WMP + q * 16);
#pragma unroll
        for (int i = 0; i < 4; ++i) {
            float4 v = *(const float4*)(src + 4 * i);
            dst[2 * i]     = pack2bf(v.x, v.y);
            dst[2 * i + 1] = pack2bf(v.z, v.w);
        }
    }
    {   // stage x tile [ch][128 pos]
        int ch = tid >> 2, part = tid & 3;
        const float* src = buf + ((size_t)(b * 64 + ch)) * LP;
        uint* dst = (uint*)(sX + ch * WXP + part * 32);
#pragma unroll
        for (int i = 0; i < 8; ++i) {
            int l = l0 + part * 32 + 4 * i;
            float4 v = load4g(src, l, L);
            dst[2 * i]     = pack2bf(v.x, v.y);
            dst[2 * i + 1] = pack2bf(v.z, v.w);
        }
    }
    __syncthreads();
    const int w = tid >> 6, l = tid & 63, g = l >> 4, c = l & 15;
    f32x4 acc[2][4];
#pragma unroll
    for (int mt = 0; mt < 4; ++mt) {
        float4 bv = *(const float4*)(bias + 16 * mt + 4 * g);
#pragma unroll
        for (int tt = 0; tt < 2; ++tt) {
            acc[tt][mt][0] = bv.x; acc[tt][mt][1] = bv.y;
            acc[tt][mt][2] = bv.z; acc[tt][mt][3] = bv.w;
        }
    }
#pragma unroll
    for (int kk = 0; kk < 2; ++kk) {
        bf16x8 af[4];
#pragma unroll
        for (int mt = 0; mt < 4; ++mt)
            af[mt] = *(bf16x8*)(sW + (16 * mt + c) * WMP + kk * 32 + 8 * g);
#pragma unroll
        for (int tt = 0; tt < 2; ++tt) {
            const int nl = 32 * w + 16 * tt + c;
            bf16x8 xb;
#pragma unroll
            for (int j = 0; j < 8; ++j)
                xb[j] = (short)sX[(kk * 32 + 8 * g + j) * WXP + nl];
#pragma unroll
            for (int mt = 0; mt < 4; ++mt)
                acc[tt][mt] = __builtin_amdgcn_mfma_f32_16x16x32_bf16(af[mt], xb, acc[tt][mt], 0, 0, 0);
        }
    }
#pragma unroll
    for (int tt = 0; tt < 2; ++tt) {
        const int nl = 32 * w + 16 * tt + c;
        if (l0 + nl < L) {
#pragma unroll
            for (int mt = 0; mt < 4; ++mt)
#pragma unroll
                for (int r = 0; r < 4; ++r) {
                    int m = 16 * mt + 4 * g + r;
                    buf[((size_t)(b * 64 + m)) * LP + l0 + nl] = acc[tt][mt][r];
                }
        }
    }
}

// ---------------- fused MLP: A += W2 * gelu(W1 * inorm(A) + b1) + b2 (bf16 MFMA) ----------
#define W1P 72
#define W2P 136
#define XP  66
#define MP  136

__global__ __launch_bounds__(256) void mlp_kernel(float* __restrict__ A,
                                                  const float2* __restrict__ stats,
                                                  const float* __restrict__ W1,
                                                  const float* __restrict__ b1,
                                                  const float* __restrict__ W2,
                                                  const float* __restrict__ b2) {
    __shared__ ushort sW1[128 * W1P];
    __shared__ ushort sW2[64 * W2P];
    __shared__ ushort sX [64 * XP];
    __shared__ ushort sMid[64 * MP];
    const int b  = blockIdx.y;
    const int n0 = blockIdx.x * 64;
    const int tid = threadIdx.x;

    {   // stage W1 (128x64)
        int row = tid >> 1, half = tid & 1;
        const float* src = W1 + row * 64 + half * 32;
        uint* dst = (uint*)(sW1 + row * W1P + half * 32);
#pragma unroll
        for (int i = 0; i < 8; ++i) {
            float4 v = *(const float4*)(src + 4 * i);
            dst[2 * i]     = pack2bf(v.x, v.y);
            dst[2 * i + 1] = pack2bf(v.z, v.w);
        }
    }
    {   // stage W2 (64x128)
        int row = tid >> 2, q = tid & 3;
        const float* src = W2 + row * 128 + q * 32;
        uint* dst = (uint*)(sW2 + row * W2P + q * 32);
#pragma unroll
        for (int i = 0; i < 8; ++i) {
            float4 v = *(const float4*)(src + 4 * i);
            dst[2 * i]     = pack2bf(v.x, v.y);
            dst[2 * i + 1] = pack2bf(v.z, v.w);
        }
    }
    {   // stage xn tile
        int ch = tid >> 2, part = tid & 3;
        float2 st = stats[b * 64 + ch];
        const float* src = A + ((size_t)(b * 64 + ch)) * S_LEN + n0 + part * 16;
        uint* dst = (uint*)(sX + ch * XP + part * 16);
#pragma unroll
        for (int i = 0; i < 4; ++i) {
            float4 v = *(const float4*)(src + 4 * i);
            v.x = (v.x - st.x) * st.y; v.y = (v.y - st.x) * st.y;
            v.z = (v.z - st.x) * st.y; v.w = (v.w - st.x) * st.y;
            dst[2 * i]     = pack2bf(v.x, v.y);
            dst[2 * i + 1] = pack2bf(v.z, v.w);
        }
    }
    __syncthreads();

    const int w = tid >> 6;
    const int l = tid & 63;
    const int g = l >> 4;
    const int c = l & 15;
    const int nl = 16 * w + c;

    bf16x8 xb[2];
#pragma unroll
    for (int kk = 0; kk < 2; ++kk)
#pragma unroll
        for (int j = 0; j < 8; ++j)
            xb[kk][j] = (short)sX[(kk * 32 + 8 * g + j) * XP + nl];

    f32x4 acc1[8];
#pragma unroll
    for (int mt = 0; mt < 8; ++mt) {
        float4 bv = *(const float4*)(b1 + 16 * mt + 4 * g);
        acc1[mt][0] = bv.x; acc1[mt][1] = bv.y; acc1[mt][2] = bv.z; acc1[mt][3] = bv.w;
    }
#pragma unroll
    for (int kk = 0; kk < 2; ++kk) {
#pragma unroll
        for (int mt = 0; mt < 8; ++mt) {
            bf16x8 af = *(bf16x8*)(sW1 + (16 * mt + c) * W1P + kk * 32 + 8 * g);
            acc1[mt] = __builtin_amdgcn_mfma_f32_16x16x32_bf16(af, xb[kk], acc1[mt], 0, 0, 0);
        }
    }
#pragma unroll
    for (int mt = 0; mt < 8; ++mt)
#pragma unroll
        for (int r = 0; r < 4; ++r)
            sMid[nl * MP + 16 * mt + 4 * g + r] = f2bf(gelu1(acc1[mt][r]));

    bf16x8 mb[4];
#pragma unroll
    for (int kk = 0; kk < 4; ++kk)
        mb[kk] = *(bf16x8*)(sMid + nl * MP + kk * 32 + 8 * g);

    f32x4 acc2[4];
#pragma unroll
    for (int mt = 0; mt < 4; ++mt) {
        float4 bv = *(const float4*)(b2 + 16 * mt + 4 * g);
        acc2[mt][0] = bv.x; acc2[mt][1] = bv.y; acc2[mt][2] = bv.z; acc2[mt][3] = bv.w;
    }
#pragma unroll
    for (int kk = 0; kk < 4; ++kk) {
#pragma unroll
        for (int mt = 0; mt < 4; ++mt) {
            bf16x8 af = *(bf16x8*)(sW2 + (16 * mt + c) * W2P + kk * 32 + 8 * g);
            acc2[mt] = __builtin_amdgcn_mfma_f32_16x16x32_bf16(af, mb[kk], acc2[mt], 0, 0, 0);
        }
    }
#pragma unroll
    for (int mt = 0; mt < 4; ++mt) {
#pragma unroll
        for (int r = 0; r < 4; ++r) {
            int m = 16 * mt + 4 * g + r;
            float* p = A + ((size_t)(b * 64 + m)) * S_LEN + n0 + nl;
            *p = acc2[mt][r] + *p;
        }
    }
}

// ---------------- fused head: out = W2 * gelu(W1 * A + b1) + b2 (bf16 MFMA) ----------
#define HXP 66
#define HMP 40

__global__ __launch_bounds__(256) void head_kernel(const float* __restrict__ A,
                                                   float* __restrict__ out,
                                                   const float* __restrict__ W1,  // 32x64
                                                   const float* __restrict__ b1,
                                                   const float* __restrict__ W2,  // 64x32
                                                   const float* __restrict__ b2) {
    __shared__ ushort sW1[32 * 72];
    __shared__ ushort sW2[64 * HMP];
    __shared__ ushort sX [64 * HXP];
    __shared__ ushort sMid[64 * HMP];
    const int b = blockIdx.y, n0 = blockIdx.x * 64, tid = threadIdx.x;
    {   // W1: 32 rows x 64
        int row = tid >> 3, q = tid & 7;
        const float* src = W1 + row * 64 + q * 8;
        uint* dst = (uint*)(sW1 + row * 72 + q * 8);
#pragma unroll
        for (int i = 0; i < 2; ++i) {
            float4 v = *(const float4*)(src + 4 * i);
            dst[2 * i] = pack2bf(v.x, v.y); dst[2 * i + 1] = pack2bf(v.z, v.w);
        }
    }
    {   // W2: 64 rows x 32
        int row = tid >> 2, q = tid & 3;
        const float* src = W2 + row * 32 + q * 8;
        uint* dst = (uint*)(sW2 + row * HMP + q * 8);
#pragma unroll
        for (int i = 0; i < 2; ++i) {
            float4 v = *(const float4*)(src + 4 * i);
            dst[2 * i] = pack2bf(v.x, v.y); dst[2 * i + 1] = pack2bf(v.z, v.w);
        }
    }
    {   // X: 64ch x 64pos (no norm)
        int ch = tid >> 2, part = tid & 3;
        const float* src = A + ((size_t)(b * 64 + ch)) * S_LEN + n0 + part * 16;
        uint* dst = (uint*)(sX + ch * HXP + part * 16);
#pragma unroll
        for (int i = 0; i < 4; ++i) {
            float4 v = *(const float4*)(src + 4 * i);
            dst[2 * i] = pack2bf(v.x, v.y); dst[2 * i + 1] = pack2bf(v.z, v.w);
        }
    }
    __syncthreads();
    const int w = tid >> 6, l = tid & 63, g = l >> 4, c = l & 15;
    const int nl = 16 * w + c;
    bf16x8 xb[2];
#pragma unroll
    for (int kk = 0; kk < 2; ++kk)
#pragma unroll
        for (int j = 0; j < 8; ++j)
            xb[kk][j] = (short)sX[(kk * 32 + 8 * g + j) * HXP + nl];
    f32x4 acc1[2];
#pragma unroll
    for (int mt = 0; mt < 2; ++mt) {
        float4 bv = *(const float4*)(b1 + 16 * mt + 4 * g);
        acc1[mt][0] = bv.x; acc1[mt][1] = bv.y; acc1[mt][2] = bv.z; acc1[mt][3] = bv.w;
    }
#pragma unroll
    for (int kk = 0; kk < 2; ++kk)
#pragma unroll
        for (int mt = 0; mt < 2; ++mt) {
            bf16x8 af = *(bf16x8*)(sW1 + (16 * mt + c) * 72 + kk * 32 + 8 * g);
            acc1[mt] = __builtin_amdgcn_mfma_f32_16x16x32_bf16(af, xb[kk], acc1[mt], 0, 0, 0);
        }
#pragma unroll
    for (int mt = 0; mt < 2; ++mt)
#pragma unroll
        for (int r = 0; r < 4; ++r)
            sMid[nl * HMP + 16 * mt + 4 * g + r] = f2bf(gelu1(acc1[mt][r]));
    bf16x8 mb = *(bf16x8*)(sMid + nl * HMP + 8 * g);
    f32x4 acc2[4];
#pragma unroll
    for (int mt = 0; mt < 4; ++mt) {
        float4 bv = *(const float4*)(b2 + 16 * mt + 4 * g);
        acc2[mt][0] = bv.x; acc2[mt][1] = bv.y; acc2[mt][2] = bv.z; acc2[mt][3] = bv.w;
    }
#pragma unroll
    for (int mt = 0; mt < 4; ++mt) {
        bf16x8 af = *(bf16x8*)(sW2 + (16 * mt + c) * HMP + 8 * g);
        acc2[mt] = __builtin_amdgcn_mfma_f32_16x16x32_bf16(af, mb, acc2[mt], 0, 0, 0);
    }
#pragma unroll
    for (int mt = 0; mt < 4; ++mt)
#pragma unroll
        for (int r = 0; r < 4; ++r) {
            int m = 16 * mt + 4 * g + r;
            out[((size_t)(b * 64 + m)) * S_LEN + n0 + nl] = acc2[mt][r];
        }
}

// ---------------- DWT level in LDS, 8 outputs/thread, float4 windows ----------------
__device__ __forceinline__ void dwt8_core(const float* __restrict__ xb,
                                          float* __restrict__ lo, float* __restrict__ hi) {
#pragma unroll
    for (int j = 0; j < 8; ++j) {
        float l0 = 0.f, h0 = 0.f;
#pragma unroll
        for (int k = 0; k < 16; ++k) {
            float v = xb[2 * j + k + 2];
            l0 = fmaf(v, c_dlo[15 - k], l0);
            h0 = fmaf(v, c_dhi[15 - k], h0);
        }
        lo[j] = l0; hi[j] = h0;
    }
}

__device__ __forceinline__ void dwt_lds_v2(const float* __restrict__ in, int Sin,
                                           float* __restrict__ aout,
                                           float* __restrict__ dout_g, int Lout, int tid) {
    const int NT = (Lout + 7) >> 3;
    for (int g = tid; g < NT; g += 256) {
        float xb[32];
        const int base = 16 * g - 16;
        if (base >= 0 && base + 32 <= Sin) {
#pragma unroll
            for (int q = 0; q < 8; ++q)
                *(float4*)(xb + 4 * q) = *(const float4*)(in + base + 4 * q);
        } else {
#pragma unroll
            for (int loc = 0; loc < 32; ++loc) {
                int i = base + loc;
                i = (i < 0) ? (-1 - i) : i;
                i = (i >= Sin) ? (2 * Sin - 1 - i) : i;
                xb[loc] = in[i];
            }
        }
        float lo[8], hi[8];
        dwt8_core(xb, lo, hi);
        const int t0 = 8 * g;
        if (t0 + 8 <= Lout) {
            *(float4*)(aout + t0)     = make_float4(lo[0], lo[1], lo[2], lo[3]);
            *(float4*)(aout + t0 + 4) = make_float4(lo[4], lo[5], lo[6], lo[7]);
        } else {
#pragma unroll
            for (int j = 0; j < 8; ++j) if (t0 + j < Lout) aout[t0 + j] = lo[j];
        }
        store4g(dout_g, t0,     Lout, make_float4(hi[0], hi[1], hi[2], hi[3]));
        store4g(dout_g, t0 + 4, Lout, make_float4(hi[4], hi[5], hi[6], hi[7]));
    }
}

__global__ __launch_bounds__(256) void dwt_full_kernel(const float* __restrict__ A,
                                                       const float2* __restrict__ stats,
                                                       float* __restrict__ d1,
                                                       float* __restrict__ d2,
                                                       float* __restrict__ d3,
                                                       float* __restrict__ d4,
                                                       float* __restrict__ a4) {
    __shared__ float bufA[4104];
    __shared__ float bufB[2060];
    const int row = blockIdx.x;
    const int tid = threadIdx.x;
    const float2 st = stats[row];
    const float* x = A + (size_t)row * S_LEN;
    float* d1r = d1 + (size_t)row * LP1;

    // level 1: normalize on the fly; lo -> bufA, hi -> d1 (global)
    for (int g = tid; g < 513; g += 256) {
        const int base = 16 * g - 16;
        float xb[32];
        if (base >= 0 && base + 32 <= S_LEN) {
#pragma unroll
            for (int q = 0; q < 8; ++q) {
                float4 v = *(const float4*)(x + base + 4 * q);
                v.x = (v.x - st.x) * st.y; v.y = (v.y - st.x) * st.y;
                v.z = (v.z - st.x) * st.y; v.w = (v.w - st.x) * st.y;
                *(float4*)(xb + 4 * q) = v;
            }
        } else {
#pragma unroll
            for (int loc = 0; loc < 32; ++loc) {
                int i = base + loc;
                i = (i < 0) ? (-1 - i) : i;
                i = (i >= S_LEN) ? (2 * S_LEN - 1 - i) : i;
                xb[loc] = (x[i] - st.x) * st.y;
            }
        }
        float lo[8], hi[8];
        dwt8_core(xb, lo, hi);
        const int t0 = 8 * g;
#pragma unroll
        for (int j = 0; j < 8; ++j)
            if (t0 + j < L1v) bufA[t0 + j] = lo[j];
        store4g(d1r, t0,     L1v, make_float4(hi[0], hi[1], hi[2], hi[3]));
        store4g(d1r, t0 + 4, L1v, make_float4(hi[4], hi[5], hi[6], hi[7]));
    }
    __syncthreads();
    dwt_lds_v2(bufA, L1v, bufB, d2 + (size_t)row * LP2, L2v, tid);
    __syncthreads();
    dwt_lds_v2(bufB, L2v, bufA, d3 + (size_t)row * LP3, L3v, tid);
    __syncthreads();
    dwt_lds_v2(bufA, L3v, bufB, d4 + (size_t)row * LP4, L4v, tid);
    __syncthreads();
    float* a4r = a4 + (size_t)row * LP4;
    for (int i = tid; i < 132; i += 256)
        *(float4*)(a4r + 4 * i) = *(const float4*)(bufB + 4 * i);
}

// ---------------- IDWT 8 outputs/thread from a/d windows (float4 reads) ----------------
__device__ __forceinline__ void idwt8_regs(const float* __restrict__ a,
                                           const float* __restrict__ d,
                                           int g, int Lc, float* __restrict__ y) {
    float av[12], dv[12];
    const int m0 = 4 * g;
    if (m0 + 12 <= Lc) {
#pragma unroll
        for (int q = 0; q < 3; ++q) {
            *(float4*)(av + 4 * q) = *(const float4*)(a + m0 + 4 * q);
            *(float4*)(dv + 4 * q) = *(const float4*)(d + m0 + 4 * q);
        }
    } else {
#pragma unroll
        for (int jj = 0; jj < 12; ++jj) {
            int m = m0 + jj;
            bool ok = (m < Lc);
            av[jj] = ok ? a[m] : 0.f;
            dv[jj] = ok ? d[m] : 0.f;
        }
    }
#pragma unroll
    for (int e = 0; e < 4; ++e) {
        float ye = 0.f, yo = 0.f;
#pragma unroll
        for (int j = 0; j < 8; ++j) {
            ye = fmaf(av[e + j], c_dlo[2 * j + 1], ye);
            ye = fmaf(dv[e + j], c_dlo[14 - 2 * j], ye);
            yo = fmaf(av[e + j], c_dlo[2 * j], yo);
            yo = fmaf(dv[e + j], -c_dlo[15 - 2 * j], yo);
        }
        y[2 * e] = ye;
        y[2 * e + 1] = yo;
    }
}

__device__ __forceinline__ void idwt_lds_v2(const float* __restrict__ a,
                                            const float* __restrict__ d,
                                            int Lc, int Lout, float* __restrict__ out, int tid) {
    const int NT = (Lout + 7) >> 3;
    for (int g = tid; g < NT; g += 256) {
        float y[8];
        idwt8_regs(a, d, g, Lc, y);
        const int t0 = 8 * g;
        if (t0 + 8 <= Lout) {
            *(float4*)(out + t0)     = make_float4(y[0], y[1], y[2], y[3]);
            *(float4*)(out + t0 + 4) = make_float4(y[4], y[5], y[6], y[7]);
        } else {
#pragma unroll
            for (int j = 0; j < 8; ++j) if (t0 + j < Lout) out[t0 + j] = y[j];
        }
    }
}

__device__ __forceinline__ void gload_lds(const float* __restrict__ src, int Lv,
                                          float* __restrict__ dst, int tid) {
    const int NG = (Lv + 3) >> 2;
    for (int i = tid; i < NG; i += 256)
        *(float4*)(dst + 4 * i) = load4g(src, 4 * i, Lv);
}

__global__ __launch_bounds__(256) void idwt_full_kernel(const float* __restrict__ a4,
                                                        const float* __restrict__ d4,
                                                        const float* __restrict__ d3,
                                                        const float* __restrict__ d2,
                                                        const float* __restrict__ d1,
                                                        float* __restrict__ h,
                                                        const float* __restrict__ xs,
                                                        float2* __restrict__ statsOut) {
    __shared__ float bufY[4104];
    __shared__ float bufA[4104];
    __shared__ float bufD[4104];
    const int row = blockIdx.x;
    const int tid = threadIdx.x;

    gload_lds(a4 + (size_t)row * LP4, L4v, bufA, tid);
    gload_lds(d4 + (size_t)row * LP4, L4v, bufD, tid);
    __syncthreads();
    idwt_lds_v2(bufA, bufD, L4v, 1038, bufY, tid);
    __syncthreads();
    gload_lds(d3 + (size_t)row * LP3, L3v, bufD, tid);
    __syncthreads();
    idwt_lds_v2(bufY, bufD, L3v, 2060, bufA, tid);
    __syncthreads();
    gload_lds(d2 + (size_t)row * LP2, L2v, bufD, tid);
    __syncthreads();
    idwt_lds_v2(bufA, bufD, L2v, 4104, bufY, tid);
    __syncthreads();
    gload_lds(d1 + (size_t)row * LP1, L1v, bufD, tid);
    __syncthreads();

    // level 1 (8192) fused: h += gelu(y + xs); accumulate stats of updated h
    float* hrow = h + (size_t)row * S_LEN;
    const float* srow = xs + (size_t)row * S_LEN;
    float s = 0.f, ss = 0.f;
#pragma unroll
    for (int it = 0; it < 4; ++it) {
        const int g = it * 256 + tid;       // 0..1023
        float y[8];
        idwt8_regs(bufY, bufD, g, L1v, y);
        const int t0 = 8 * g;
#pragma unroll
        for (int q = 0; q < 2; ++q) {
            float4 sv = *(const float4*)(srow + t0 + 4 * q);
            float4 hv = *(const float4*)(hrow + t0 + 4 * q);
            hv.x += gelu1(y[4 * q + 0] + sv.x);
            hv.y += gelu1(y[4 * q + 1] + sv.y);
            hv.z += gelu1(y[4 * q + 2] + sv.z);
            hv.w += gelu1(y[4 * q + 3] + sv.w);
            *(float4*)(hrow + t0 + 4 * q) = hv;
            s += hv.x + hv.y + hv.z + hv.w;
            ss = fmaf(hv.x, hv.x, fmaf(hv.y, hv.y, fmaf(hv.z, hv.z, fmaf(hv.w, hv.w, ss))));
        }
    }
    for (int off = 32; off > 0; off >>= 1) {
        s  += __shfl_down(s, off, 64);
        ss += __shfl_down(ss, off, 64);
    }
    __syncthreads();
    int lane = tid & 63, wv = tid >> 6;
    if (lane == 0) { bufA[wv] = s; bufA[4 + wv] = ss; }
    __syncthreads();
    if (tid == 0) {
        float tot  = bufA[0] + bufA[1] + bufA[2] + bufA[3];
        float tot2 = bufA[4] + bufA[5] + bufA[6] + bufA[7];
        float mean = tot * (1.0f / S_LEN);
        float var  = tot2 * (1.0f / S_LEN) - mean * mean;
        statsOut[row] = make_float2(mean, rsqrtf(var + 1e-5f));
    }
}

extern "C" void kernel_launch(void* const* d_in, const int* in_sizes, int n_in,
                              void* d_out, int out_size, void* d_ws, size_t ws_size,
                              hipStream_t stream) {
    const float* x       = (const float*)d_in[0];
    const float* lift_w  = (const float*)d_in[1];
    const float* lift_b  = (const float*)d_in[2];
    const float* blk_w_w = (const float*)d_in[3];
    const float* blk_w_b = (const float*)d_in[4];
    const float* blk_ca_w= (const float*)d_in[5];
    const float* blk_ca_b= (const float*)d_in[6];
    const float* blk_cd_w= (const float*)d_in[7];
    const float* blk_cd_b= (const float*)d_in[8];
    const float* blk_m1_w= (const float*)d_in[9];
    const float* blk_m1_b= (const float*)d_in[10];
    const float* blk_m2_w= (const float*)d_in[11];
    const float* blk_m2_b= (const float*)d_in[12];
    const float* p1_w    = (const float*)d_in[13];
    const float* p1_b    = (const float*)d_in[14];
    const float* p2_w    = (const float*)d_in[15];
    const float* p2_b    = (const float*)d_in[16];

    float* ws = (float*)d_ws;
    const size_t T32 = (size_t)NBC * S_LEN;
    float* A  = ws;                                  // h / xo (residual stream)
    float* Cc = ws + 2 * T32;                        // xs (conv out)
    float* d1 = ws + 4 * T32;
    float* d2 = d1 + (size_t)NBC * LP1;
    float* d3 = d2 + (size_t)NBC * LP2;
    float* d4 = d3 + (size_t)NBC * LP3;
    float* ap0 = d4 + (size_t)NBC * LP4;
    float* ap1 = ap0 + (size_t)NBC * 4104;
    float2* statsBuf = (float2*)(ap1 + (size_t)NBC * 4104);

    dim3 blk(256);

    lift_kernel<<<(NBC * S_LEN) / 256, blk, 0, stream>>>(x, lift_w, lift_b, A);

    for (int i = 0; i < 4; ++i) {
        const float* w_w  = blk_w_w  + (size_t)i * 64 * 64 * 3;
        const float* w_b  = blk_w_b  + (size_t)i * 64;
        const float* ca_w = blk_ca_w + (size_t)i * 64 * 64;
        const float* ca_b = blk_ca_b + (size_t)i * 64;
        const float* cd_w = blk_cd_w + (size_t)i * 4 * 64 * 64;
        const float* cd_b = blk_cd_b + (size_t)i * 4 * 64;
        const float* m1_w = blk_m1_w + (size_t)i * 128 * 64;
        const float* m1_b = blk_m1_b + (size_t)i * 128;
        const float* m2_w = blk_m2_w + (size_t)i * 64 * 128;
        const float* m2_b = blk_m2_b + (size_t)i * 64;

        stats_kernel<<<NBC, blk, 0, stream>>>(A, statsBuf);
        conv3_mfma_kernel<<<dim3(S_LEN / 128, B_N), blk, 0, stream>>>(A, Cc, w_w, w_b, statsBuf);
        dwt_full_kernel<<<NBC, blk, 0, stream>>>(A, statsBuf, d1, d2, d3, d4, ap1);

        wmix_kernel<<<dim3(69, B_N), blk, 0, stream>>>(d1, d2, d3, d4, ap1,
                                                       cd_w, cd_b, ca_w, ca_b);

        idwt_full_kernel<<<NBC, blk, 0, stream>>>(ap1, d4, d3, d2, d1, A, Cc, statsBuf);
        mlp_kernel<<<dim3(S_LEN / 64, B_N), blk, 0, stream>>>(A, statsBuf, m1_w, m1_b, m2_w, m2_b);
    }

    head_kernel<<<dim3(S_LEN / 64, B_N), blk, 0, stream>>>(A, (float*)d_out,
                                                           p1_w, p1_b, p2_w, p2_b);
}